// Round 6
// baseline (407.783 us; speedup 1.0000x reference)
//
#include <hip/hip_runtime.h>
#include <hip/hip_bf16.h>

// Problem dims (fixed)
#define Bq 4
#define Sq 2048
#define Eq 768
#define Hq 3
#define Dq 256
#define BHq (Bq*Hq)

typedef __hip_bfloat16 bf16;
typedef __attribute__((ext_vector_type(8))) short bf16x8;
typedef __attribute__((ext_vector_type(4))) float f32x4;

__device__ __forceinline__ f32x4 mfma16(bf16x8 a, bf16x8 b, f32x4 c) {
    return __builtin_amdgcn_mfma_f32_16x16x32_bf16(a, b, c, 0, 0, 0);
}

__device__ __forceinline__ short f2bf(float x) {
    bf16 b = __float2bfloat16(x);
    return *(short*)&b;
}

__device__ __forceinline__ float bf2f(short s) {
    bf16 b = *reinterpret_cast<bf16*>(&s);
    return __bfloat162float(b);
}

__device__ __forceinline__ bf16x8 cvt8(float4 a, float4 b) {
    bf16x8 r;
    r[0] = f2bf(a.x); r[1] = f2bf(a.y); r[2] = f2bf(a.z); r[3] = f2bf(a.w);
    r[4] = f2bf(b.x); r[5] = f2bf(b.y); r[6] = f2bf(b.z); r[7] = f2bf(b.w);
    return r;
}

// async global->LDS, 16B per lane; LDS dest = wave-uniform base + lane*16
__device__ __forceinline__ void gl2lds16(const bf16* g, bf16* l) {
    __builtin_amdgcn_global_load_lds(
        (const __attribute__((address_space(1))) unsigned int*)g,
        (__attribute__((address_space(3))) unsigned int*)l,
        16, 0, 0);
}

// ---------------------------------------------------------------------------
// Fused prep: X f32->bf16 convert (blocks [0,9216)) + weight transposes
// (blocks [9216,11520)). All blocks 256 threads.
// ---------------------------------------------------------------------------
__global__ __launch_bounds__(256) void prep_kernel(
        const float* __restrict__ Xk, const float* __restrict__ Xv,
        const float* __restrict__ Xq, bf16* __restrict__ Xb,
        const float* __restrict__ WK, const float* __restrict__ WV,
        const float* __restrict__ WQ, const float* __restrict__ Wo,
        bf16* __restrict__ WtK, bf16* __restrict__ Wot) {
    const int blk = blockIdx.x;
    const int tid = threadIdx.x;

    if (blk < 9216) {   // convert
        const int t = blk / 3072;
        const int i = blk % 3072;
        const float* X = (t == 0) ? Xk : (t == 1) ? Xv : Xq;
        size_t idx = ((size_t)i * 256 + tid) * 8;
        float4 a = *(const float4*)&X[idx];
        float4 b = *(const float4*)&X[idx + 4];
        *(bf16x8*)&Xb[(size_t)t * ((size_t)Bq * Sq * Eq) + idx] = cvt8(a, b);
        return;
    }

    __shared__ float tile[32][33];
    const float* in;
    bf16* out;
    int R, C, bx, by;
    if (blk < 10944) {            // QKV weight transposes
        int r  = blk - 9216;      // [0,1728)
        int t  = r / 576;
        int rr = r % 576;
        int batch = rr / 192;
        int tl = rr % 192;
        bx = tl & 7; by = tl >> 3;
        R = Eq; C = Dq;
        const float* Wsrc = (t == 0) ? WK : (t == 1) ? WV : WQ;
        in  = Wsrc + (size_t)batch * R * C;
        out = WtK + (size_t)t * ((size_t)Hq * Eq * Dq) + (size_t)batch * R * C;
    } else {                      // Wo transpose
        int rr = blk - 10944;     // [0,576)
        bx = rr % 24; by = rr / 24;
        R = Eq; C = Eq;
        in  = Wo;
        out = Wot;
    }
    const int tx = tid & 31;
    const int ty = tid >> 5;
#pragma unroll
    for (int i = ty; i < 32; i += 8)
        tile[i][tx] = in[(size_t)(by * 32 + i) * C + bx * 32 + tx];
    __syncthreads();
#pragma unroll
    for (int i = ty; i < 32; i += 8)
        out[(size_t)(bx * 32 + i) * R + by * 32 + tx] = __float2bfloat16(tile[tx][i]);
}

// ---------------------------------------------------------------------------
// Projection GEMM (R3 version: BK=32 double-buffer + coalesced LDS epilogue).
// ---------------------------------------------------------------------------
__global__ __launch_bounds__(256) void proj_kernel(
        const bf16* __restrict__ Xb, const bf16* __restrict__ Wt,
        bf16* __restrict__ Kp, bf16* __restrict__ Vt, bf16* __restrict__ Qp) {
    const int sel = blockIdx.y;
    const int x   = blockIdx.x;
    const int xcd = x & 7;
    const int kk0 = x >> 3;               // [0,48)
    const int mt  = xcd * 8 + (kk0 / 6);  // [0,64)
    const int nt  = kk0 % 6;              // [0,6)
    const bf16* X = Xb + (size_t)sel * ((size_t)Bq * Sq * Eq);
    const bf16* W = Wt + (size_t)sel * ((size_t)Hq * Eq * Dq);

    __shared__ struct {
        bf16 A[2][128 * 32];
        bf16 B[2][128 * 32];
    } sm;
    auto& As = sm.A;
    auto& Bs = sm.B;

    const int tid  = threadIdx.x;
    const int lane = tid & 63;
    const int w    = tid >> 6;
    const int quad = lane >> 4;
    const int l16  = lane & 15;
    const int wm   = (w & 1) * 64;
    const int wn   = (w >> 1) * 64;

    const int m0 = mt * 128;
    const int n0 = nt * 128;

    int srow[2], skc[2];
#pragma unroll
    for (int i = 0; i < 2; ++i) {
        int ci  = (w * 2 + i) * 64 + lane;      // [0,512) chunk-of-8 index
        srow[i] = ci >> 2;                      // [0,128)
        skc[i]  = (ci & 3) ^ ((srow[i] >> 1) & 3);
    }

#define STAGE(buf, k0)                                                        \
    {                                                                         \
        _Pragma("unroll")                                                     \
        for (int i = 0; i < 2; ++i) {                                         \
            gl2lds16(&X[(size_t)(m0 + srow[i]) * Eq + (k0) + skc[i] * 8],     \
                     &As[buf][(w * 2 + i) * 512]);                            \
            gl2lds16(&W[(size_t)(n0 + srow[i]) * Eq + (k0) + skc[i] * 8],     \
                     &Bs[buf][(w * 2 + i) * 512]);                            \
        }                                                                     \
    }

    STAGE(0, 0);
    __syncthreads();

    f32x4 acc[4][4] = {};

    for (int s = 0; s < 24; ++s) {
        if (s + 1 < 24) STAGE((s + 1) & 1, (s + 1) * 32);
        const bf16* A  = As[s & 1];
        const bf16* Bv = Bs[s & 1];
        bf16x8 af[4], bfr[4];
#pragma unroll
        for (int mi = 0; mi < 4; ++mi) {
            int row = wm + mi * 16 + l16;
            int c   = quad ^ ((row >> 1) & 3);
            af[mi]  = *(const bf16x8*)&A[row * 32 + c * 8];
        }
#pragma unroll
        for (int ni = 0; ni < 4; ++ni) {
            int row = wn + ni * 16 + l16;
            int c   = quad ^ ((row >> 1) & 3);
            bfr[ni] = *(const bf16x8*)&Bv[row * 32 + c * 8];
        }
#pragma unroll
        for (int mi = 0; mi < 4; ++mi)
#pragma unroll
            for (int ni = 0; ni < 4; ++ni)
                acc[mi][ni] = mfma16(af[mi], bfr[ni], acc[mi][ni]);
        __syncthreads();
    }
#undef STAGE

    // epilogue: restage C-tile in LDS, then coalesced 256B-row stores
    bf16* ct = (bf16*)&sm;           // 128x128 bf16 = 32KB
    const int b  = m0 / Sq;
    const int s0 = m0 % Sq;
    const int h  = n0 >> 8;
    const int d0 = n0 & 255;
    const int bh = b * Hq + h;

    if (sel == 1) {
#pragma unroll
        for (int mi = 0; mi < 4; ++mi)
#pragma unroll
            for (int ni = 0; ni < 4; ++ni)
#pragma unroll
                for (int r = 0; r < 4; ++r) {
                    int row = wn + ni * 16 + l16;           // d_local
                    int col = wm + mi * 16 + quad * 4 + r;  // s_local
                    ct[row * 128 + (((col >> 3) ^ (row & 15)) * 8) + (col & 7)] =
                        __float2bfloat16(acc[mi][ni][r]);
                }
    } else {
#pragma unroll
        for (int mi = 0; mi < 4; ++mi)
#pragma unroll
            for (int ni = 0; ni < 4; ++ni)
#pragma unroll
                for (int r = 0; r < 4; ++r) {
                    int row = wm + mi * 16 + quad * 4 + r;  // s_local
                    int col = wn + ni * 16 + l16;           // n_local
                    ct[row * 128 + (((col >> 3) ^ (row & 15)) * 8) + (col & 7)] =
                        __float2bfloat16(acc[mi][ni][r]);
                }
    }
    __syncthreads();
    {
        const int rr = tid >> 4;   // 0..15
        const int c  = tid & 15;   // 0..15
#pragma unroll
        for (int p = 0; p < 8; ++p) {
            int r  = p * 16 + rr;
            int cp = c ^ (r & 15);
            bf16x8 v = *(const bf16x8*)&ct[r * 128 + cp * 8];
            if (sel == 1)
                *(bf16x8*)&Vt[(size_t)(bh * Dq + d0 + r) * Sq + s0 + c * 8] = v;
            else if (sel == 0)
                *(bf16x8*)&Kp[(size_t)(bh * Sq + s0 + r) * Dq + d0 + c * 8] = v;
            else
                *(bf16x8*)&Qp[(size_t)(bh * Sq + s0 + r) * Dq + d0 + c * 8] = v;
        }
    }
}

// ---------------------------------------------------------------------------
// Split-K flash attention v3: EXACT R3 inner code (66.4us measured), with
// ONE change: Ks and Vs share a single 32KB LDS buffer (they are never live
// simultaneously: K is consumed by QK, V only by PV).
//   per tile: load K->regs | sync | write K | sync | QK | softmax+Pl |
//             load V->regs | sync (Ks dead) | write V (same buffer) |
//             sync | PV
// vreg lives across exactly one barrier (not across any MFMA cluster), so
// the register profile matches R3 (~124 VGPR, no spills). LDS 72->40KB
// -> 3 blocks/CU (launch_bounds(256,3)); extra barriers are covered by the
// additional resident blocks.
// ---------------------------------------------------------------------------
__global__ __launch_bounds__(256, 3) void attn_kernel(
        const bf16* __restrict__ Qp, const bf16* __restrict__ Kp,
        const bf16* __restrict__ Vt, bf16* __restrict__ Z,
        bf16* __restrict__ Opart, float* __restrict__ lpart) {
    __shared__ bf16 KVs[64 * 256];   // 32KB: K-tile during QK, V-tile during PV
    __shared__ bf16 Pl[4 * 16 * 64]; // 8KB

    const float SCALE = 0.022097086912079608f;  // 1/sqrt(2048)

    const int id    = blockIdx.x;
    const int lane8 = id & 7;
    const int j     = id >> 3;
    const int W     = lane8 * 216 + j;
    const int bh    = W / 144;
    const int w144  = W % 144;
    int g = 0;
#pragma unroll
    for (int gg = 1; gg < 8; ++gg)
        if (w144 >= 2 * gg * (gg + 1)) g = gg;
    const int rem   = w144 - 2 * g * (g + 1);
    const int qb    = g * 4 + rem / (g + 1);
    const int chunk = rem % (g + 1);
    const int t0    = chunk * 4;
    const int t1    = min(t0 + 4, qb + 1);
    const bool single = (qb < 4);

    const int tid  = threadIdx.x;
    const int lane = tid & 63;
    const int w    = tid >> 6;
    const int quad = lane >> 4;
    const int l16  = lane & 15;
    const int q0   = qb * 64 + w * 16;

    bf16x8 qf[8];
    {
        const bf16* Qbase = Qp + (size_t)(bh * Sq + q0 + l16) * Dq;
#pragma unroll
        for (int c = 0; c < 8; ++c)
            qf[c] = *(const bf16x8*)&Qbase[c * 32 + quad * 8];
    }

    const bf16* Kbh = Kp + (size_t)bh * Sq * Dq;
    const bf16* Vbh = Vt + (size_t)bh * Dq * Sq;

    f32x4 o[16] = {};
    float lsum[4] = {0.0f, 0.0f, 0.0f, 0.0f};

    for (int t = t0; t < t1; ++t) {
        const int k0 = t * 64;

        // K tile -> regs (transient)
        bf16x8 kreg[8];
#pragma unroll
        for (int p = 0; p < 8; ++p) {
            int c = p * 256 + tid;
            int row = c >> 5, cc = c & 31;
            kreg[p] = *(const bf16x8*)&Kbh[(size_t)(k0 + row) * Dq + cc * 8];
        }

        __syncthreads();   // prev tile's PV reads of KVs (V) fully done
#pragma unroll
        for (int p = 0; p < 8; ++p) {
            int c = p * 256 + tid;
            int row = c >> 5, cc = c & 31;
            *(bf16x8*)&KVs[row * 256 + (cc ^ (row & 7)) * 8] = kreg[p];
        }
        __syncthreads();

        // QK^T
        f32x4 sf[4] = {};
#pragma unroll
        for (int c = 0; c < 8; ++c) {
            int cc = c * 4 + quad;
#pragma unroll
            for (int ni = 0; ni < 4; ++ni) {
                int key = ni * 16 + l16;
                bf16x8 kf = *(const bf16x8*)&KVs[key * 256 + (cc ^ (key & 7)) * 8];
                sf[ni] = mfma16(qf[c], kf, sf[ni]);
            }
        }

        // softmax + Pl write
        const bool diag = (t == qb);
#pragma unroll
        for (int ni = 0; ni < 4; ++ni) {
#pragma unroll
            for (int r = 0; r < 4; ++r) {
                float p = __expf(sf[ni][r] * SCALE);
                if (diag) {
                    int kg = k0 + ni * 16 + l16;
                    int qg = q0 + quad * 4 + r;
                    if (kg > qg) p = 0.0f;
                }
                lsum[r] += p;
                int row = quad * 4 + r;
                int col = ni * 16 + l16;
                int cc  = col >> 3;
                Pl[w * 1024 + row * 64 + (cc ^ (row & 7)) * 8 + (col & 7)] =
                    __float2bfloat16(p);
            }
        }

        // V tile -> regs (in flight across the barrier)
        bf16x8 vreg[8];
#pragma unroll
        for (int p = 0; p < 8; ++p) {
            int c = p * 256 + tid;
            int row = c >> 3, cc = c & 7;
            vreg[p] = *(const bf16x8*)&Vbh[(size_t)row * Sq + k0 + cc * 8];
        }

        __syncthreads();   // all waves' QK reads of KVs done; Ks dead
#pragma unroll
        for (int p = 0; p < 8; ++p) {
            int c = p * 256 + tid;
            int row = c >> 3, cc = c & 7;
            *(bf16x8*)&KVs[row * 64 + (cc ^ (row & 7)) * 8] = vreg[p];
        }
        __syncthreads();

        // PV
#pragma unroll
        for (int c2 = 0; c2 < 2; ++c2) {
            int cc = c2 * 4 + quad;
            bf16x8 af = *(const bf16x8*)&Pl[w * 1024 + l16 * 64 + (cc ^ (l16 & 7)) * 8];
#pragma unroll
            for (int ni = 0; ni < 16; ++ni) {
                int d = ni * 16 + l16;
                bf16x8 vf = *(const bf16x8*)&KVs[d * 64 + (cc ^ (d & 7)) * 8];
                o[ni] = mfma16(af, vf, o[ni]);
            }
        }
    }

#pragma unroll
    for (int off = 1; off < 16; off <<= 1)
#pragma unroll
        for (int r = 0; r < 4; ++r)
            lsum[r] += __shfl_xor(lsum[r], off);

    if (single) {
        const int b = bh / Hq, h = bh % Hq;
        float rinv[4];
#pragma unroll
        for (int r = 0; r < 4; ++r) rinv[r] = 1.0f / lsum[r];
#pragma unroll
        for (int ni = 0; ni < 16; ++ni) {
#pragma unroll
            for (int r = 0; r < 4; ++r) {
                int s = q0 + quad * 4 + r;
                int e = h * Dq + ni * 16 + l16;
                Z[(size_t)(b * Sq + s) * Eq + e] = __float2bfloat16(o[ni][r] * rinv[r]);
            }
        }
    } else {
        const int slot = bh * 144 + w144;
        bf16* Ob = Opart + (size_t)slot * (64 * 256);
#pragma unroll
        for (int ni = 0; ni < 16; ++ni) {
#pragma unroll
            for (int r = 0; r < 4; ++r) {
                int row = w * 16 + quad * 4 + r;
                int col = ni * 16 + l16;
                Ob[row * 256 + col] = __float2bfloat16(o[ni][r]);
            }
        }
        if (l16 == 0) {
#pragma unroll
            for (int r = 0; r < 4; ++r)
                lpart[(size_t)slot * 64 + w * 16 + quad * 4 + r] = lsum[r];
        }
    }
}

// ---------------------------------------------------------------------------
// Combine partials (unchanged).
// ---------------------------------------------------------------------------
__global__ __launch_bounds__(256) void combine_kernel(
        const bf16* __restrict__ Opart, const float* __restrict__ lpart,
        bf16* __restrict__ Z) {
    const int qb = blockIdx.x;
    const int bh = blockIdx.y;
    if (qb < 4) return;
    const int g = qb >> 2;
    const int nch = g + 1;
    const int wbase = 2 * g * (g + 1) + (qb & 3) * (g + 1);
    const int slot0 = bh * 144 + wbase;

    const int tid = threadIdx.x;
    const int r   = tid >> 2;
    const int cs  = tid & 3;

    float l = 0.0f;
    for (int c = 0; c < nch; ++c)
        l += lpart[(size_t)(slot0 + c) * 64 + r];
    const float rinv = 1.0f / l;

    const int b = bh / Hq, h = bh % Hq;
    const int s = qb * 64 + r;
    bf16* zrow = Z + (size_t)(b * Sq + s) * Eq + h * Dq;

#pragma unroll
    for (int seg = 0; seg < 8; ++seg) {
        int col0 = cs * 64 + seg * 8;
        float acc[8] = {};
        for (int c = 0; c < nch; ++c) {
            bf16x8 v = *(const bf16x8*)&Opart[(size_t)(slot0 + c) * (64 * 256) + r * 256 + col0];
#pragma unroll
            for (int i = 0; i < 8; ++i) {
                short sv = v[i];
                acc[i] += bf2f(sv);
            }
        }
        bf16x8 outv;
#pragma unroll
        for (int i = 0; i < 8; ++i) outv[i] = f2bf(acc[i] * rinv);
        *(bf16x8*)&zrow[col0] = outv;
    }
}

// ---------------------------------------------------------------------------
// Output projection (R1 structure: double-buffered BK=32, one barrier/step).
// ---------------------------------------------------------------------------
__global__ __launch_bounds__(256) void outproj_kernel(
        const bf16* __restrict__ Z, const bf16* __restrict__ Wot,
        const float* __restrict__ bo, float* __restrict__ out) {
    const int x   = blockIdx.x;
    const int xcd = x & 7;
    const int kk0 = x >> 3;               // [0,48)
    const int mt  = xcd * 8 + (kk0 / 6);  // [0,64)
    const int nt  = kk0 % 6;              // [0,6)

    __shared__ bf16 As[2][128 * 32];
    __shared__ bf16 Bs[2][128 * 32];

    const int tid  = threadIdx.x;
    const int lane = tid & 63;
    const int w    = tid >> 6;
    const int quad = lane >> 4;
    const int l16  = lane & 15;
    const int wm   = (w & 1) * 64;
    const int wn   = (w >> 1) * 64;

    const int m0 = mt * 128;
    const int n0 = nt * 128;

    int srow[2], skc[2];
#pragma unroll
    for (int i = 0; i < 2; ++i) {
        int ci  = (w * 2 + i) * 64 + lane;
        srow[i] = ci >> 2;
        skc[i]  = (ci & 3) ^ ((srow[i] >> 1) & 3);
    }

#define STAGE2(buf, k0)                                                       \
    {                                                                         \
        _Pragma("unroll")                                                     \
        for (int i = 0; i < 2; ++i) {                                         \
            gl2lds16(&Z[(size_t)(m0 + srow[i]) * Eq + (k0) + skc[i] * 8],     \
                     &As[buf][(w * 2 + i) * 512]);                            \
            gl2lds16(&Wot[(size_t)(n0 + srow[i]) * Eq + (k0) + skc[i] * 8],   \
                     &Bs[buf][(w * 2 + i) * 512]);                            \
        }                                                                     \
    }

    STAGE2(0, 0);
    __syncthreads();

    f32x4 acc[4][4] = {};

    for (int s = 0; s < 24; ++s) {
        if (s + 1 < 24) STAGE2((s + 1) & 1, (s + 1) * 32);
        const bf16* A  = As[s & 1];
        const bf16* Bv = Bs[s & 1];
        bf16x8 af[4], bfr[4];
#pragma unroll
        for (int mi = 0; mi < 4; ++mi) {
            int row = wm + mi * 16 + l16;
            int c   = quad ^ ((row >> 1) & 3);
            af[mi]  = *(const bf16x8*)&A[row * 32 + c * 8];
        }
#pragma unroll
        for (int ni = 0; ni < 4; ++ni) {
            int row = wn + ni * 16 + l16;
            int c   = quad ^ ((row >> 1) & 3);
            bfr[ni] = *(const bf16x8*)&Bv[row * 32 + c * 8];
        }
#pragma unroll
        for (int mi = 0; mi < 4; ++mi)
#pragma unroll
            for (int ni = 0; ni < 4; ++ni)
                acc[mi][ni] = mfma16(af[mi], bfr[ni], acc[mi][ni]);
        __syncthreads();
    }
#undef STAGE2

#pragma unroll
    for (int ni = 0; ni < 4; ++ni) {
        int n = n0 + wn + ni * 16 + l16;
        float bias = bo[n];
#pragma unroll
        for (int mi = 0; mi < 4; ++mi) {
#pragma unroll
            for (int r = 0; r < 4; ++r) {
                int m = m0 + wm + mi * 16 + quad * 4 + r;
                out[(size_t)m * Eq + n] = acc[mi][ni][r] + bias;
            }
        }
    }
}

// ---------------------------------------------------------------------------
extern "C" void kernel_launch(void* const* d_in, const int* in_sizes, int n_in,
                              void* d_out, int out_size, void* d_ws, size_t ws_size,
                              hipStream_t stream) {
    const float* Xk = (const float*)d_in[0];
    const float* Xv = (const float*)d_in[1];
    const float* Xq = (const float*)d_in[2];
    const float* WK = (const float*)d_in[3];
    const float* WV = (const float*)d_in[4];
    const float* WQ = (const float*)d_in[5];
    const float* Wo = (const float*)d_in[6];
    const float* bo = (const float*)d_in[7];
    float* out = (float*)d_out;

    // workspace layout (bf16 elements)
    bf16* ws = (bf16*)d_ws;
    const size_t WSZ  = (size_t)Hq * Eq * Dq;   // 589824
    const size_t QKV  = (size_t)BHq * Sq * Dq;  // 6291456
    bf16* WtK = ws;                 // [t][h][d][e], t=0 K /1 V /2 Q
    bf16* WtO = WtK + 3 * WSZ;      // [out_e][in_e]
    bf16* Qp  = WtO + (size_t)Eq * Eq;
    bf16* Kp  = Qp + QKV;           // [b,h,s,d]
    bf16* Vt  = Kp + QKV;           // [b,h,d,s]
    bf16* Zb  = Vt + QKV;           // [b,s,e]
    bf16* Opart = Zb + QKV;         // 1728 x 64 x 256 bf16
    float* lpart = (float*)(Opart + (size_t)1728 * 64 * 256);
    // Xb aliases Opart: proj reads Xb before attn writes Opart (stream order).
    bf16* Xb = Opart;

    prep_kernel<<<11520, 256, 0, stream>>>(Xk, Xv, Xq, Xb, WK, WV, WQ, Wo, WtK, WtO);
    proj_kernel<<<dim3(384, 3), 256, 0, stream>>>(Xb, WtK, Kp, Vt, Qp);
    attn_kernel<<<1728, 256, 0, stream>>>(Qp, Kp, Vt, Zb, Opart, lpart);
    combine_kernel<<<dim3(32, BHq), 256, 0, stream>>>(Opart, lpart, Zb);
    outproj_kernel<<<384, 256, 0, stream>>>(Zb, WtO, bo, out);
}

// Round 7
// 394.693 us; speedup vs baseline: 1.0332x; 1.0332x over previous
//
#include <hip/hip_runtime.h>
#include <hip/hip_bf16.h>

// Problem dims (fixed)
#define Bq 4
#define Sq 2048
#define Eq 768
#define Hq 3
#define Dq 256
#define BHq (Bq*Hq)

typedef __hip_bfloat16 bf16;
typedef __attribute__((ext_vector_type(8))) short bf16x8;
typedef __attribute__((ext_vector_type(4))) float f32x4;

__device__ __forceinline__ f32x4 mfma16(bf16x8 a, bf16x8 b, f32x4 c) {
    return __builtin_amdgcn_mfma_f32_16x16x32_bf16(a, b, c, 0, 0, 0);
}

__device__ __forceinline__ short f2bf(float x) {
    bf16 b = __float2bfloat16(x);
    return *(short*)&b;
}

__device__ __forceinline__ float bf2f(short s) {
    bf16 b = *reinterpret_cast<bf16*>(&s);
    return __bfloat162float(b);
}

__device__ __forceinline__ bf16x8 cvt8(float4 a, float4 b) {
    bf16x8 r;
    r[0] = f2bf(a.x); r[1] = f2bf(a.y); r[2] = f2bf(a.z); r[3] = f2bf(a.w);
    r[4] = f2bf(b.x); r[5] = f2bf(b.y); r[6] = f2bf(b.z); r[7] = f2bf(b.w);
    return r;
}

// async global->LDS, 16B per lane; LDS dest = wave-uniform base + lane*16
__device__ __forceinline__ void gl2lds16(const bf16* g, bf16* l) {
    __builtin_amdgcn_global_load_lds(
        (const __attribute__((address_space(1))) unsigned int*)g,
        (__attribute__((address_space(3))) unsigned int*)l,
        16, 0, 0);
}

// ---------------------------------------------------------------------------
// Fused prep: X f32->bf16 convert (blocks [0,9216)) + weight transposes
// (blocks [9216,11520)). All blocks 256 threads.
// ---------------------------------------------------------------------------
__global__ __launch_bounds__(256) void prep_kernel(
        const float* __restrict__ Xk, const float* __restrict__ Xv,
        const float* __restrict__ Xq, bf16* __restrict__ Xb,
        const float* __restrict__ WK, const float* __restrict__ WV,
        const float* __restrict__ WQ, const float* __restrict__ Wo,
        bf16* __restrict__ WtK, bf16* __restrict__ Wot) {
    const int blk = blockIdx.x;
    const int tid = threadIdx.x;

    if (blk < 9216) {   // convert
        const int t = blk / 3072;
        const int i = blk % 3072;
        const float* X = (t == 0) ? Xk : (t == 1) ? Xv : Xq;
        size_t idx = ((size_t)i * 256 + tid) * 8;
        float4 a = *(const float4*)&X[idx];
        float4 b = *(const float4*)&X[idx + 4];
        *(bf16x8*)&Xb[(size_t)t * ((size_t)Bq * Sq * Eq) + idx] = cvt8(a, b);
        return;
    }

    __shared__ float tile[32][33];
    const float* in;
    bf16* out;
    int R, C, bx, by;
    if (blk < 10944) {            // QKV weight transposes
        int r  = blk - 9216;      // [0,1728)
        int t  = r / 576;
        int rr = r % 576;
        int batch = rr / 192;
        int tl = rr % 192;
        bx = tl & 7; by = tl >> 3;
        R = Eq; C = Dq;
        const float* Wsrc = (t == 0) ? WK : (t == 1) ? WV : WQ;
        in  = Wsrc + (size_t)batch * R * C;
        out = WtK + (size_t)t * ((size_t)Hq * Eq * Dq) + (size_t)batch * R * C;
    } else {                      // Wo transpose
        int rr = blk - 10944;     // [0,576)
        bx = rr % 24; by = rr / 24;
        R = Eq; C = Eq;
        in  = Wo;
        out = Wot;
    }
    const int tx = tid & 31;
    const int ty = tid >> 5;
#pragma unroll
    for (int i = ty; i < 32; i += 8)
        tile[i][tx] = in[(size_t)(by * 32 + i) * C + bx * 32 + tx];
    __syncthreads();
#pragma unroll
    for (int i = ty; i < 32; i += 8)
        out[(size_t)(bx * 32 + i) * R + by * 32 + tx] = __float2bfloat16(tile[tx][i]);
}

// ---------------------------------------------------------------------------
// Projection GEMM (R3 version: BK=32 double-buffer + coalesced LDS epilogue).
// ---------------------------------------------------------------------------
__global__ __launch_bounds__(256) void proj_kernel(
        const bf16* __restrict__ Xb, const bf16* __restrict__ Wt,
        bf16* __restrict__ Kp, bf16* __restrict__ Vt, bf16* __restrict__ Qp) {
    const int sel = blockIdx.y;
    const int x   = blockIdx.x;
    const int xcd = x & 7;
    const int kk0 = x >> 3;               // [0,48)
    const int mt  = xcd * 8 + (kk0 / 6);  // [0,64)
    const int nt  = kk0 % 6;              // [0,6)
    const bf16* X = Xb + (size_t)sel * ((size_t)Bq * Sq * Eq);
    const bf16* W = Wt + (size_t)sel * ((size_t)Hq * Eq * Dq);

    __shared__ struct {
        bf16 A[2][128 * 32];
        bf16 B[2][128 * 32];
    } sm;
    auto& As = sm.A;
    auto& Bs = sm.B;

    const int tid  = threadIdx.x;
    const int lane = tid & 63;
    const int w    = tid >> 6;
    const int quad = lane >> 4;
    const int l16  = lane & 15;
    const int wm   = (w & 1) * 64;
    const int wn   = (w >> 1) * 64;

    const int m0 = mt * 128;
    const int n0 = nt * 128;

    int srow[2], skc[2];
#pragma unroll
    for (int i = 0; i < 2; ++i) {
        int ci  = (w * 2 + i) * 64 + lane;      // [0,512) chunk-of-8 index
        srow[i] = ci >> 2;                      // [0,128)
        skc[i]  = (ci & 3) ^ ((srow[i] >> 1) & 3);
    }

#define STAGE(buf, k0)                                                        \
    {                                                                         \
        _Pragma("unroll")                                                     \
        for (int i = 0; i < 2; ++i) {                                         \
            gl2lds16(&X[(size_t)(m0 + srow[i]) * Eq + (k0) + skc[i] * 8],     \
                     &As[buf][(w * 2 + i) * 512]);                            \
            gl2lds16(&W[(size_t)(n0 + srow[i]) * Eq + (k0) + skc[i] * 8],     \
                     &Bs[buf][(w * 2 + i) * 512]);                            \
        }                                                                     \
    }

    STAGE(0, 0);
    __syncthreads();

    f32x4 acc[4][4] = {};

    for (int s = 0; s < 24; ++s) {
        if (s + 1 < 24) STAGE((s + 1) & 1, (s + 1) * 32);
        const bf16* A  = As[s & 1];
        const bf16* Bv = Bs[s & 1];
        bf16x8 af[4], bfr[4];
#pragma unroll
        for (int mi = 0; mi < 4; ++mi) {
            int row = wm + mi * 16 + l16;
            int c   = quad ^ ((row >> 1) & 3);
            af[mi]  = *(const bf16x8*)&A[row * 32 + c * 8];
        }
#pragma unroll
        for (int ni = 0; ni < 4; ++ni) {
            int row = wn + ni * 16 + l16;
            int c   = quad ^ ((row >> 1) & 3);
            bfr[ni] = *(const bf16x8*)&Bv[row * 32 + c * 8];
        }
#pragma unroll
        for (int mi = 0; mi < 4; ++mi)
#pragma unroll
            for (int ni = 0; ni < 4; ++ni)
                acc[mi][ni] = mfma16(af[mi], bfr[ni], acc[mi][ni]);
        __syncthreads();
    }
#undef STAGE

    // epilogue: restage C-tile in LDS, then coalesced 256B-row stores
    bf16* ct = (bf16*)&sm;           // 128x128 bf16 = 32KB
    const int b  = m0 / Sq;
    const int s0 = m0 % Sq;
    const int h  = n0 >> 8;
    const int d0 = n0 & 255;
    const int bh = b * Hq + h;

    if (sel == 1) {
#pragma unroll
        for (int mi = 0; mi < 4; ++mi)
#pragma unroll
            for (int ni = 0; ni < 4; ++ni)
#pragma unroll
                for (int r = 0; r < 4; ++r) {
                    int row = wn + ni * 16 + l16;           // d_local
                    int col = wm + mi * 16 + quad * 4 + r;  // s_local
                    ct[row * 128 + (((col >> 3) ^ (row & 15)) * 8) + (col & 7)] =
                        __float2bfloat16(acc[mi][ni][r]);
                }
    } else {
#pragma unroll
        for (int mi = 0; mi < 4; ++mi)
#pragma unroll
            for (int ni = 0; ni < 4; ++ni)
#pragma unroll
                for (int r = 0; r < 4; ++r) {
                    int row = wm + mi * 16 + quad * 4 + r;  // s_local
                    int col = wn + ni * 16 + l16;           // n_local
                    ct[row * 128 + (((col >> 3) ^ (row & 15)) * 8) + (col & 7)] =
                        __float2bfloat16(acc[mi][ni][r]);
                }
    }
    __syncthreads();
    {
        const int rr = tid >> 4;   // 0..15
        const int c  = tid & 15;   // 0..15
#pragma unroll
        for (int p = 0; p < 8; ++p) {
            int r  = p * 16 + rr;
            int cp = c ^ (r & 15);
            bf16x8 v = *(const bf16x8*)&ct[r * 128 + cp * 8];
            if (sel == 1)
                *(bf16x8*)&Vt[(size_t)(bh * Dq + d0 + r) * Sq + s0 + c * 8] = v;
            else if (sel == 0)
                *(bf16x8*)&Kp[(size_t)(bh * Sq + s0 + r) * Dq + d0 + c * 8] = v;
            else
                *(bf16x8*)&Qp[(size_t)(bh * Sq + s0 + r) * Dq + d0 + c * 8] = v;
        }
    }
}

// ---------------------------------------------------------------------------
// Split-K flash attention v4: R3 phase structure EXACTLY (load K+V regs at
// tile top -> sync -> ds_write both -> sync -> QK -> softmax+Pl -> PV, 2
// barriers/tile, same swizzles, same per-wave register profile), but scaled
// to QBLK=128 q-rows via 512-thread / 8-wave blocks. Each wave owns 16
// q-rows as before; each K/V tile-visit now serves 128 rows -> tile-visits
// halve (6336 -> 3264), halving L2 K/V re-read volume, and wave occupancy
// doubles (2 blocks x 8 waves = 16 waves/CU). LDS = 32(Ks)+32(Vs)+16(Pl)
// = 80KB -> 2 blocks/CU. Causal mask applied unconditionally (the last two
// tiles of each q-block straddle the diagonal).
// Split-K: per bh, q-block qb' has 2qb'+2 tiles, chunked by 4:
// nch=(qb'+2)>>1, cumulative S[qb'], 72 chunks/bh, 864 blocks total.
// ---------------------------------------------------------------------------
__global__ __launch_bounds__(512, 4) void attn_kernel(
        const bf16* __restrict__ Qp, const bf16* __restrict__ Kp,
        const bf16* __restrict__ Vt, bf16* __restrict__ Z,
        bf16* __restrict__ Opart, float* __restrict__ lpart) {
    __shared__ bf16 Ks[64 * 256];     // 32KB
    __shared__ bf16 Vs[256 * 64];     // 32KB
    __shared__ bf16 Pl[8 * 16 * 64];  // 16KB

    const float SCALE = 0.022097086912079608f;  // 1/sqrt(2048)

    // chunk-count prefix sums: S[qb'] = chunks before q-block qb'
    const int id    = blockIdx.x;     // [0,864)
    const int lane8 = id & 7;         // XCD
    const int j     = id >> 3;        // [0,108)
    const int W     = lane8 * 108 + j;
    const int bh    = W / 72;
    const int w72   = W % 72;
    int qb = 0;
    {
        const int S1=1,S2=2,S3=4,S4=6,S5=9,S6=12,S7=16,S8=20,S9=25,S10=30,
                  S11=36,S12=42,S13=49,S14=56,S15=64;
        if (w72 >= S1)  qb = 1;
        if (w72 >= S2)  qb = 2;
        if (w72 >= S3)  qb = 3;
        if (w72 >= S4)  qb = 4;
        if (w72 >= S5)  qb = 5;
        if (w72 >= S6)  qb = 6;
        if (w72 >= S7)  qb = 7;
        if (w72 >= S8)  qb = 8;
        if (w72 >= S9)  qb = 9;
        if (w72 >= S10) qb = 10;
        if (w72 >= S11) qb = 11;
        if (w72 >= S12) qb = 12;
        if (w72 >= S13) qb = 13;
        if (w72 >= S14) qb = 14;
        if (w72 >= S15) qb = 15;
    }
    const int Sarr[16] = {0,1,2,4,6,9,12,16,20,25,30,36,42,49,56,64};
    const int chunk = w72 - Sarr[qb];
    const int t0    = chunk * 4;
    const int t1    = min(t0 + 4, 2 * qb + 2);
    const bool single = (qb < 2);     // nch == 1

    const int tid  = threadIdx.x;     // [0,512)
    const int lane = tid & 63;
    const int w    = tid >> 6;        // [0,8)
    const int quad = lane >> 4;
    const int l16  = lane & 15;
    const int q0   = qb * 128 + w * 16;

    bf16x8 qf[8];
    {
        const bf16* Qbase = Qp + (size_t)(bh * Sq + q0 + l16) * Dq;
#pragma unroll
        for (int c = 0; c < 8; ++c)
            qf[c] = *(const bf16x8*)&Qbase[c * 32 + quad * 8];
    }

    const bf16* Kbh = Kp + (size_t)bh * Sq * Dq;
    const bf16* Vbh = Vt + (size_t)bh * Dq * Sq;

    f32x4 o[16] = {};
    float lsum[4] = {0.0f, 0.0f, 0.0f, 0.0f};

    for (int t = t0; t < t1; ++t) {
        const int k0 = t * 64;

        // K+V tile -> regs (512 threads: 4 chunks each)
        bf16x8 kreg[4], vreg[4];
#pragma unroll
        for (int p = 0; p < 4; ++p) {
            int c = p * 512 + tid;
            int row = c >> 5, cc = c & 31;
            kreg[p] = *(const bf16x8*)&Kbh[(size_t)(k0 + row) * Dq + cc * 8];
        }
#pragma unroll
        for (int p = 0; p < 4; ++p) {
            int c = p * 512 + tid;
            int row = c >> 3, cc = c & 7;
            vreg[p] = *(const bf16x8*)&Vbh[(size_t)row * Sq + k0 + cc * 8];
        }

        __syncthreads();   // prev tile's Ks/Vs reads fully done
#pragma unroll
        for (int p = 0; p < 4; ++p) {
            int c = p * 512 + tid;
            int row = c >> 5, cc = c & 31;
            *(bf16x8*)&Ks[row * 256 + (cc ^ (row & 7)) * 8] = kreg[p];
        }
#pragma unroll
        for (int p = 0; p < 4; ++p) {
            int c = p * 512 + tid;
            int row = c >> 3, cc = c & 7;
            *(bf16x8*)&Vs[row * 64 + (cc ^ (row & 7)) * 8] = vreg[p];
        }
        __syncthreads();

        // QK^T (per-wave, 16 q rows)
        f32x4 sf[4] = {};
#pragma unroll
        for (int c = 0; c < 8; ++c) {
            int cc = c * 4 + quad;
#pragma unroll
            for (int ni = 0; ni < 4; ++ni) {
                int key = ni * 16 + l16;
                bf16x8 kf = *(const bf16x8*)&Ks[key * 256 + (cc ^ (key & 7)) * 8];
                sf[ni] = mfma16(qf[c], kf, sf[ni]);
            }
        }

        // softmax + Pl write (unconditional causal mask)
#pragma unroll
        for (int ni = 0; ni < 4; ++ni) {
#pragma unroll
            for (int r = 0; r < 4; ++r) {
                float p = __expf(sf[ni][r] * SCALE);
                int kg = k0 + ni * 16 + l16;
                int qg = q0 + quad * 4 + r;
                if (kg > qg) p = 0.0f;
                lsum[r] += p;
                int row = quad * 4 + r;
                int col = ni * 16 + l16;
                int cc  = col >> 3;
                Pl[w * 1024 + row * 64 + (cc ^ (row & 7)) * 8 + (col & 7)] =
                    __float2bfloat16(p);
            }
        }

        // PV (Pl rows are wave-private; Vs covered by the barrier above)
#pragma unroll
        for (int c2 = 0; c2 < 2; ++c2) {
            int cc = c2 * 4 + quad;
            bf16x8 af = *(const bf16x8*)&Pl[w * 1024 + l16 * 64 + (cc ^ (l16 & 7)) * 8];
#pragma unroll
            for (int ni = 0; ni < 16; ++ni) {
                int d = ni * 16 + l16;
                bf16x8 vf = *(const bf16x8*)&Vs[d * 64 + (cc ^ (d & 7)) * 8];
                o[ni] = mfma16(af, vf, o[ni]);
            }
        }
    }

    // reduce lsum across the 16 key-lanes
#pragma unroll
    for (int off = 1; off < 16; off <<= 1)
#pragma unroll
        for (int r = 0; r < 4; ++r)
            lsum[r] += __shfl_xor(lsum[r], off);

    if (single) {
        const int b = bh / Hq, h = bh % Hq;
        float rinv[4];
#pragma unroll
        for (int r = 0; r < 4; ++r) rinv[r] = 1.0f / lsum[r];
#pragma unroll
        for (int ni = 0; ni < 16; ++ni) {
#pragma unroll
            for (int r = 0; r < 4; ++r) {
                int s = q0 + quad * 4 + r;
                int e = h * Dq + ni * 16 + l16;
                Z[(size_t)(b * Sq + s) * Eq + e] = __float2bfloat16(o[ni][r] * rinv[r]);
            }
        }
    } else {
        const int slot = bh * 72 + w72;
        bf16* Ob = Opart + (size_t)slot * (128 * 256);
#pragma unroll
        for (int ni = 0; ni < 16; ++ni) {
#pragma unroll
            for (int r = 0; r < 4; ++r) {
                int row = w * 16 + quad * 4 + r;
                int col = ni * 16 + l16;
                Ob[row * 256 + col] = __float2bfloat16(o[ni][r]);
            }
        }
        if (l16 == 0) {
#pragma unroll
            for (int r = 0; r < 4; ++r)
                lpart[(size_t)slot * 128 + w * 16 + quad * 4 + r] = lsum[r];
        }
    }
}

// ---------------------------------------------------------------------------
// Combine partials for QBLK=128 slots. Grid (16, 12); qb' < 2 skipped.
// ---------------------------------------------------------------------------
__global__ __launch_bounds__(256) void combine_kernel(
        const bf16* __restrict__ Opart, const float* __restrict__ lpart,
        bf16* __restrict__ Z) {
    const int qb = blockIdx.x;
    const int bh = blockIdx.y;
    if (qb < 2) return;
    const int Sarr[16] = {0,1,2,4,6,9,12,16,20,25,30,36,42,49,56,64};
    const int nch   = (qb + 2) >> 1;
    const int slot0 = bh * 72 + Sarr[qb];

    const int tid = threadIdx.x;
    const int r   = tid >> 1;    // [0,128)
    const int cs  = tid & 1;     // [0,2)

    float l = 0.0f;
    for (int c = 0; c < nch; ++c)
        l += lpart[(size_t)(slot0 + c) * 128 + r];
    const float rinv = 1.0f / l;

    const int b = bh / Hq, h = bh % Hq;
    const int s = qb * 128 + r;
    bf16* zrow = Z + (size_t)(b * Sq + s) * Eq + h * Dq;

#pragma unroll
    for (int seg = 0; seg < 16; ++seg) {
        int col0 = cs * 128 + seg * 8;
        float acc[8] = {};
        for (int c = 0; c < nch; ++c) {
            bf16x8 v = *(const bf16x8*)&Opart[(size_t)(slot0 + c) * (128 * 256) + r * 256 + col0];
#pragma unroll
            for (int i = 0; i < 8; ++i) {
                short sv = v[i];
                acc[i] += bf2f(sv);
            }
        }
        bf16x8 outv;
#pragma unroll
        for (int i = 0; i < 8; ++i) outv[i] = f2bf(acc[i] * rinv);
        *(bf16x8*)&zrow[col0] = outv;
    }
}

// ---------------------------------------------------------------------------
// Output projection (R1 structure: double-buffered BK=32, one barrier/step).
// ---------------------------------------------------------------------------
__global__ __launch_bounds__(256) void outproj_kernel(
        const bf16* __restrict__ Z, const bf16* __restrict__ Wot,
        const float* __restrict__ bo, float* __restrict__ out) {
    const int x   = blockIdx.x;
    const int xcd = x & 7;
    const int kk0 = x >> 3;               // [0,48)
    const int mt  = xcd * 8 + (kk0 / 6);  // [0,64)
    const int nt  = kk0 % 6;              // [0,6)

    __shared__ bf16 As[2][128 * 32];
    __shared__ bf16 Bs[2][128 * 32];

    const int tid  = threadIdx.x;
    const int lane = tid & 63;
    const int w    = tid >> 6;
    const int quad = lane >> 4;
    const int l16  = lane & 15;
    const int wm   = (w & 1) * 64;
    const int wn   = (w >> 1) * 64;

    const int m0 = mt * 128;
    const int n0 = nt * 128;

    int srow[2], skc[2];
#pragma unroll
    for (int i = 0; i < 2; ++i) {
        int ci  = (w * 2 + i) * 64 + lane;
        srow[i] = ci >> 2;
        skc[i]  = (ci & 3) ^ ((srow[i] >> 1) & 3);
    }

#define STAGE2(buf, k0)                                                       \
    {                                                                         \
        _Pragma("unroll")                                                     \
        for (int i = 0; i < 2; ++i) {                                         \
            gl2lds16(&Z[(size_t)(m0 + srow[i]) * Eq + (k0) + skc[i] * 8],     \
                     &As[buf][(w * 2 + i) * 512]);                            \
            gl2lds16(&Wot[(size_t)(n0 + srow[i]) * Eq + (k0) + skc[i] * 8],   \
                     &Bs[buf][(w * 2 + i) * 512]);                            \
        }                                                                     \
    }

    STAGE2(0, 0);
    __syncthreads();

    f32x4 acc[4][4] = {};

    for (int s = 0; s < 24; ++s) {
        if (s + 1 < 24) STAGE2((s + 1) & 1, (s + 1) * 32);
        const bf16* A  = As[s & 1];
        const bf16* Bv = Bs[s & 1];
        bf16x8 af[4], bfr[4];
#pragma unroll
        for (int mi = 0; mi < 4; ++mi) {
            int row = wm + mi * 16 + l16;
            int c   = quad ^ ((row >> 1) & 3);
            af[mi]  = *(const bf16x8*)&A[row * 32 + c * 8];
        }
#pragma unroll
        for (int ni = 0; ni < 4; ++ni) {
            int row = wn + ni * 16 + l16;
            int c   = quad ^ ((row >> 1) & 3);
            bfr[ni] = *(const bf16x8*)&Bv[row * 32 + c * 8];
        }
#pragma unroll
        for (int mi = 0; mi < 4; ++mi)
#pragma unroll
            for (int ni = 0; ni < 4; ++ni)
                acc[mi][ni] = mfma16(af[mi], bfr[ni], acc[mi][ni]);
        __syncthreads();
    }
#undef STAGE2

#pragma unroll
    for (int ni = 0; ni < 4; ++ni) {
        int n = n0 + wn + ni * 16 + l16;
        float bias = bo[n];
#pragma unroll
        for (int mi = 0; mi < 4; ++mi) {
#pragma unroll
            for (int r = 0; r < 4; ++r) {
                int m = m0 + wm + mi * 16 + quad * 4 + r;
                out[(size_t)m * Eq + n] = acc[mi][ni][r] + bias;
            }
        }
    }
}

// ---------------------------------------------------------------------------
extern "C" void kernel_launch(void* const* d_in, const int* in_sizes, int n_in,
                              void* d_out, int out_size, void* d_ws, size_t ws_size,
                              hipStream_t stream) {
    const float* Xk = (const float*)d_in[0];
    const float* Xv = (const float*)d_in[1];
    const float* Xq = (const float*)d_in[2];
    const float* WK = (const float*)d_in[3];
    const float* WV = (const float*)d_in[4];
    const float* WQ = (const float*)d_in[5];
    const float* Wo = (const float*)d_in[6];
    const float* bo = (const float*)d_in[7];
    float* out = (float*)d_out;

    // workspace layout (bf16 elements)
    bf16* ws = (bf16*)d_ws;
    const size_t WSZ  = (size_t)Hq * Eq * Dq;   // 589824
    const size_t QKV  = (size_t)BHq * Sq * Dq;  // 6291456
    bf16* WtK = ws;                 // [t][h][d][e], t=0 K /1 V /2 Q
    bf16* WtO = WtK + 3 * WSZ;      // [out_e][in_e]
    bf16* Qp  = WtO + (size_t)Eq * Eq;
    bf16* Kp  = Qp + QKV;           // [b,h,s,d]
    bf16* Vt  = Kp + QKV;           // [b,h,d,s]
    bf16* Zb  = Vt + QKV;           // [b,s,e]
    bf16* Opart = Zb + QKV;         // 864 x 128 x 256 bf16 (= 56.6 MB)
    float* lpart = (float*)(Opart + (size_t)864 * 128 * 256);
    // Xb aliases Opart: proj reads Xb before attn writes Opart (stream order).
    bf16* Xb = Opart;

    prep_kernel<<<11520, 256, 0, stream>>>(Xk, Xv, Xq, Xb, WK, WV, WQ, Wo, WtK, WtO);
    proj_kernel<<<dim3(384, 3), 256, 0, stream>>>(Xb, WtK, Kp, Vt, Qp);
    attn_kernel<<<864, 512, 0, stream>>>(Qp, Kp, Vt, Zb, Opart, lpart);
    combine_kernel<<<dim3(16, BHq), 256, 0, stream>>>(Opart, lpart, Zb);
    outproj_kernel<<<384, 256, 0, stream>>>(Zb, WtO, bo, out);
}

// Round 8
// 318.873 us; speedup vs baseline: 1.2788x; 1.2378x over previous
//
#include <hip/hip_runtime.h>
#include <hip/hip_bf16.h>

// Problem dims (fixed)
#define Bq 4
#define Sq 2048
#define Eq 768
#define Hq 3
#define Dq 256
#define BHq (Bq*Hq)

typedef __hip_bfloat16 bf16;
typedef __attribute__((ext_vector_type(8))) short bf16x8;
typedef __attribute__((ext_vector_type(4))) float f32x4;

__device__ __forceinline__ f32x4 mfma16(bf16x8 a, bf16x8 b, f32x4 c) {
    return __builtin_amdgcn_mfma_f32_16x16x32_bf16(a, b, c, 0, 0, 0);
}

__device__ __forceinline__ short f2bf(float x) {
    bf16 b = __float2bfloat16(x);
    return *(short*)&b;
}

__device__ __forceinline__ float bf2f(short s) {
    bf16 b = *reinterpret_cast<bf16*>(&s);
    return __bfloat162float(b);
}

__device__ __forceinline__ bf16x8 cvt8(float4 a, float4 b) {
    bf16x8 r;
    r[0] = f2bf(a.x); r[1] = f2bf(a.y); r[2] = f2bf(a.z); r[3] = f2bf(a.w);
    r[4] = f2bf(b.x); r[5] = f2bf(b.y); r[6] = f2bf(b.z); r[7] = f2bf(b.w);
    return r;
}

// async global->LDS, 16B per lane; LDS dest = wave-uniform base + lane*16
__device__ __forceinline__ void gl2lds16(const bf16* g, bf16* l) {
    __builtin_amdgcn_global_load_lds(
        (const __attribute__((address_space(1))) unsigned int*)g,
        (__attribute__((address_space(3))) unsigned int*)l,
        16, 0, 0);
}

// ---------------------------------------------------------------------------
// Fused prep: X f32->bf16 convert (blocks [0,9216)) + weight transposes
// (blocks [9216,11520)). All blocks 256 threads.
// ---------------------------------------------------------------------------
__global__ __launch_bounds__(256) void prep_kernel(
        const float* __restrict__ Xk, const float* __restrict__ Xv,
        const float* __restrict__ Xq, bf16* __restrict__ Xb,
        const float* __restrict__ WK, const float* __restrict__ WV,
        const float* __restrict__ WQ, const float* __restrict__ Wo,
        bf16* __restrict__ WtK, bf16* __restrict__ Wot) {
    const int blk = blockIdx.x;
    const int tid = threadIdx.x;

    if (blk < 9216) {   // convert
        const int t = blk / 3072;
        const int i = blk % 3072;
        const float* X = (t == 0) ? Xk : (t == 1) ? Xv : Xq;
        size_t idx = ((size_t)i * 256 + tid) * 8;
        float4 a = *(const float4*)&X[idx];
        float4 b = *(const float4*)&X[idx + 4];
        *(bf16x8*)&Xb[(size_t)t * ((size_t)Bq * Sq * Eq) + idx] = cvt8(a, b);
        return;
    }

    __shared__ float tile[32][33];
    const float* in;
    bf16* out;
    int R, C, bx, by;
    if (blk < 10944) {            // QKV weight transposes
        int r  = blk - 9216;      // [0,1728)
        int t  = r / 576;
        int rr = r % 576;
        int batch = rr / 192;
        int tl = rr % 192;
        bx = tl & 7; by = tl >> 3;
        R = Eq; C = Dq;
        const float* Wsrc = (t == 0) ? WK : (t == 1) ? WV : WQ;
        in  = Wsrc + (size_t)batch * R * C;
        out = WtK + (size_t)t * ((size_t)Hq * Eq * Dq) + (size_t)batch * R * C;
    } else {                      // Wo transpose
        int rr = blk - 10944;     // [0,576)
        bx = rr % 24; by = rr / 24;
        R = Eq; C = Eq;
        in  = Wo;
        out = Wot;
    }
    const int tx = tid & 31;
    const int ty = tid >> 5;
#pragma unroll
    for (int i = ty; i < 32; i += 8)
        tile[i][tx] = in[(size_t)(by * 32 + i) * C + bx * 32 + tx];
    __syncthreads();
#pragma unroll
    for (int i = ty; i < 32; i += 8)
        out[(size_t)(bx * 32 + i) * R + by * 32 + tx] = __float2bfloat16(tile[tx][i]);
}

// ---------------------------------------------------------------------------
// Projection GEMM (R3 version: BK=32 double-buffer + coalesced LDS epilogue).
// ---------------------------------------------------------------------------
__global__ __launch_bounds__(256) void proj_kernel(
        const bf16* __restrict__ Xb, const bf16* __restrict__ Wt,
        bf16* __restrict__ Kp, bf16* __restrict__ Vt, bf16* __restrict__ Qp) {
    const int sel = blockIdx.y;
    const int x   = blockIdx.x;
    const int xcd = x & 7;
    const int kk0 = x >> 3;               // [0,48)
    const int mt  = xcd * 8 + (kk0 / 6);  // [0,64)
    const int nt  = kk0 % 6;              // [0,6)
    const bf16* X = Xb + (size_t)sel * ((size_t)Bq * Sq * Eq);
    const bf16* W = Wt + (size_t)sel * ((size_t)Hq * Eq * Dq);

    __shared__ struct {
        bf16 A[2][128 * 32];
        bf16 B[2][128 * 32];
    } sm;
    auto& As = sm.A;
    auto& Bs = sm.B;

    const int tid  = threadIdx.x;
    const int lane = tid & 63;
    const int w    = tid >> 6;
    const int quad = lane >> 4;
    const int l16  = lane & 15;
    const int wm   = (w & 1) * 64;
    const int wn   = (w >> 1) * 64;

    const int m0 = mt * 128;
    const int n0 = nt * 128;

    int srow[2], skc[2];
#pragma unroll
    for (int i = 0; i < 2; ++i) {
        int ci  = (w * 2 + i) * 64 + lane;      // [0,512) chunk-of-8 index
        srow[i] = ci >> 2;                      // [0,128)
        skc[i]  = (ci & 3) ^ ((srow[i] >> 1) & 3);
    }

#define STAGE(buf, k0)                                                        \
    {                                                                         \
        _Pragma("unroll")                                                     \
        for (int i = 0; i < 2; ++i) {                                         \
            gl2lds16(&X[(size_t)(m0 + srow[i]) * Eq + (k0) + skc[i] * 8],     \
                     &As[buf][(w * 2 + i) * 512]);                            \
            gl2lds16(&W[(size_t)(n0 + srow[i]) * Eq + (k0) + skc[i] * 8],     \
                     &Bs[buf][(w * 2 + i) * 512]);                            \
        }                                                                     \
    }

    STAGE(0, 0);
    __syncthreads();

    f32x4 acc[4][4] = {};

    for (int s = 0; s < 24; ++s) {
        if (s + 1 < 24) STAGE((s + 1) & 1, (s + 1) * 32);
        const bf16* A  = As[s & 1];
        const bf16* Bv = Bs[s & 1];
        bf16x8 af[4], bfr[4];
#pragma unroll
        for (int mi = 0; mi < 4; ++mi) {
            int row = wm + mi * 16 + l16;
            int c   = quad ^ ((row >> 1) & 3);
            af[mi]  = *(const bf16x8*)&A[row * 32 + c * 8];
        }
#pragma unroll
        for (int ni = 0; ni < 4; ++ni) {
            int row = wn + ni * 16 + l16;
            int c   = quad ^ ((row >> 1) & 3);
            bfr[ni] = *(const bf16x8*)&Bv[row * 32 + c * 8];
        }
#pragma unroll
        for (int mi = 0; mi < 4; ++mi)
#pragma unroll
            for (int ni = 0; ni < 4; ++ni)
                acc[mi][ni] = mfma16(af[mi], bfr[ni], acc[mi][ni]);
        __syncthreads();
    }
#undef STAGE

    // epilogue: restage C-tile in LDS, then coalesced 256B-row stores
    bf16* ct = (bf16*)&sm;           // 128x128 bf16 = 32KB
    const int b  = m0 / Sq;
    const int s0 = m0 % Sq;
    const int h  = n0 >> 8;
    const int d0 = n0 & 255;
    const int bh = b * Hq + h;

    if (sel == 1) {
#pragma unroll
        for (int mi = 0; mi < 4; ++mi)
#pragma unroll
            for (int ni = 0; ni < 4; ++ni)
#pragma unroll
                for (int r = 0; r < 4; ++r) {
                    int row = wn + ni * 16 + l16;           // d_local
                    int col = wm + mi * 16 + quad * 4 + r;  // s_local
                    ct[row * 128 + (((col >> 3) ^ (row & 15)) * 8) + (col & 7)] =
                        __float2bfloat16(acc[mi][ni][r]);
                }
    } else {
#pragma unroll
        for (int mi = 0; mi < 4; ++mi)
#pragma unroll
            for (int ni = 0; ni < 4; ++ni)
#pragma unroll
                for (int r = 0; r < 4; ++r) {
                    int row = wm + mi * 16 + quad * 4 + r;  // s_local
                    int col = wn + ni * 16 + l16;           // n_local
                    ct[row * 128 + (((col >> 3) ^ (row & 15)) * 8) + (col & 7)] =
                        __float2bfloat16(acc[mi][ni][r]);
                }
    }
    __syncthreads();
    {
        const int rr = tid >> 4;   // 0..15
        const int c  = tid & 15;   // 0..15
#pragma unroll
        for (int p = 0; p < 8; ++p) {
            int r  = p * 16 + rr;
            int cp = c ^ (r & 15);
            bf16x8 v = *(const bf16x8*)&ct[r * 128 + cp * 8];
            if (sel == 1)
                *(bf16x8*)&Vt[(size_t)(bh * Dq + d0 + r) * Sq + s0 + c * 8] = v;
            else if (sel == 0)
                *(bf16x8*)&Kp[(size_t)(bh * Sq + s0 + r) * Dq + d0 + c * 8] = v;
            else
                *(bf16x8*)&Qp[(size_t)(bh * Sq + s0 + r) * Dq + d0 + c * 8] = v;
        }
    }
}

// ---------------------------------------------------------------------------
// Split-K flash attention — R3-measured structure EXACTLY (66.4us, 82MB
// traffic, VGPR 124), with the ONLY change being T5 s_setprio(1)/(0)
// around the QK and PV MFMA clusters (pure scheduler hint; no dataflow,
// register-lifetime, LDS, or barrier change).
// ---------------------------------------------------------------------------
__global__ __launch_bounds__(256, 2) void attn_kernel(
        const bf16* __restrict__ Qp, const bf16* __restrict__ Kp,
        const bf16* __restrict__ Vt, bf16* __restrict__ Z,
        bf16* __restrict__ Opart, float* __restrict__ lpart) {
    __shared__ bf16 Ks[64 * 256];
    __shared__ bf16 Vs[256 * 64];
    __shared__ bf16 Pl[4 * 16 * 64];

    const float SCALE = 0.022097086912079608f;  // 1/sqrt(2048)

    const int id    = blockIdx.x;
    const int lane8 = id & 7;
    const int j     = id >> 3;
    const int W     = lane8 * 216 + j;
    const int bh    = W / 144;
    const int w144  = W % 144;
    int g = 0;
#pragma unroll
    for (int gg = 1; gg < 8; ++gg)
        if (w144 >= 2 * gg * (gg + 1)) g = gg;
    const int rem   = w144 - 2 * g * (g + 1);
    const int qb    = g * 4 + rem / (g + 1);
    const int chunk = rem % (g + 1);
    const int t0    = chunk * 4;
    const int t1    = min(t0 + 4, qb + 1);
    const bool single = (qb < 4);

    const int tid  = threadIdx.x;
    const int lane = tid & 63;
    const int w    = tid >> 6;
    const int quad = lane >> 4;
    const int l16  = lane & 15;
    const int q0   = qb * 64 + w * 16;

    bf16x8 qf[8];
    {
        const bf16* Qbase = Qp + (size_t)(bh * Sq + q0 + l16) * Dq;
#pragma unroll
        for (int c = 0; c < 8; ++c)
            qf[c] = *(const bf16x8*)&Qbase[c * 32 + quad * 8];
    }

    const bf16* Kbh = Kp + (size_t)bh * Sq * Dq;
    const bf16* Vbh = Vt + (size_t)bh * Dq * Sq;

    f32x4 o[16] = {};
    float lsum[4] = {0.0f, 0.0f, 0.0f, 0.0f};

    for (int t = t0; t < t1; ++t) {
        const int k0 = t * 64;

        bf16x8 kreg[8], vreg[8];
#pragma unroll
        for (int p = 0; p < 8; ++p) {
            int c = p * 256 + tid;
            int row = c >> 5, cc = c & 31;
            kreg[p] = *(const bf16x8*)&Kbh[(size_t)(k0 + row) * Dq + cc * 8];
        }
#pragma unroll
        for (int p = 0; p < 8; ++p) {
            int c = p * 256 + tid;
            int row = c >> 3, cc = c & 7;
            vreg[p] = *(const bf16x8*)&Vbh[(size_t)row * Sq + k0 + cc * 8];
        }

        __syncthreads();
#pragma unroll
        for (int p = 0; p < 8; ++p) {
            int c = p * 256 + tid;
            int row = c >> 5, cc = c & 31;
            *(bf16x8*)&Ks[row * 256 + (cc ^ (row & 7)) * 8] = kreg[p];
        }
#pragma unroll
        for (int p = 0; p < 8; ++p) {
            int c = p * 256 + tid;
            int row = c >> 3, cc = c & 7;
            *(bf16x8*)&Vs[row * 64 + (cc ^ (row & 7)) * 8] = vreg[p];
        }
        __syncthreads();

        f32x4 sf[4] = {};
        __builtin_amdgcn_s_setprio(1);
#pragma unroll
        for (int c = 0; c < 8; ++c) {
            int cc = c * 4 + quad;
#pragma unroll
            for (int ni = 0; ni < 4; ++ni) {
                int key = ni * 16 + l16;
                bf16x8 kf = *(const bf16x8*)&Ks[key * 256 + (cc ^ (key & 7)) * 8];
                sf[ni] = mfma16(qf[c], kf, sf[ni]);
            }
        }
        __builtin_amdgcn_s_setprio(0);

        const bool diag = (t == qb);
#pragma unroll
        for (int ni = 0; ni < 4; ++ni) {
#pragma unroll
            for (int r = 0; r < 4; ++r) {
                float p = __expf(sf[ni][r] * SCALE);
                if (diag) {
                    int kg = k0 + ni * 16 + l16;
                    int qg = q0 + quad * 4 + r;
                    if (kg > qg) p = 0.0f;
                }
                lsum[r] += p;
                int row = quad * 4 + r;
                int col = ni * 16 + l16;
                int cc  = col >> 3;
                Pl[w * 1024 + row * 64 + (cc ^ (row & 7)) * 8 + (col & 7)] =
                    __float2bfloat16(p);
            }
        }

        __builtin_amdgcn_s_setprio(1);
#pragma unroll
        for (int c2 = 0; c2 < 2; ++c2) {
            int cc = c2 * 4 + quad;
            bf16x8 af = *(const bf16x8*)&Pl[w * 1024 + l16 * 64 + (cc ^ (l16 & 7)) * 8];
#pragma unroll
            for (int ni = 0; ni < 16; ++ni) {
                int d = ni * 16 + l16;
                bf16x8 vf = *(const bf16x8*)&Vs[d * 64 + (cc ^ (d & 7)) * 8];
                o[ni] = mfma16(af, vf, o[ni]);
            }
        }
        __builtin_amdgcn_s_setprio(0);
    }

#pragma unroll
    for (int off = 1; off < 16; off <<= 1)
#pragma unroll
        for (int r = 0; r < 4; ++r)
            lsum[r] += __shfl_xor(lsum[r], off);

    if (single) {
        const int b = bh / Hq, h = bh % Hq;
        float rinv[4];
#pragma unroll
        for (int r = 0; r < 4; ++r) rinv[r] = 1.0f / lsum[r];
#pragma unroll
        for (int ni = 0; ni < 16; ++ni) {
#pragma unroll
            for (int r = 0; r < 4; ++r) {
                int s = q0 + quad * 4 + r;
                int e = h * Dq + ni * 16 + l16;
                Z[(size_t)(b * Sq + s) * Eq + e] = __float2bfloat16(o[ni][r] * rinv[r]);
            }
        }
    } else {
        const int slot = bh * 144 + w144;
        bf16* Ob = Opart + (size_t)slot * (64 * 256);
#pragma unroll
        for (int ni = 0; ni < 16; ++ni) {
#pragma unroll
            for (int r = 0; r < 4; ++r) {
                int row = w * 16 + quad * 4 + r;
                int col = ni * 16 + l16;
                Ob[row * 256 + col] = __float2bfloat16(o[ni][r]);
            }
        }
        if (l16 == 0) {
#pragma unroll
            for (int r = 0; r < 4; ++r)
                lpart[(size_t)slot * 64 + w * 16 + quad * 4 + r] = lsum[r];
        }
    }
}

// ---------------------------------------------------------------------------
// Combine partials (R3 version, unchanged).
// ---------------------------------------------------------------------------
__global__ __launch_bounds__(256) void combine_kernel(
        const bf16* __restrict__ Opart, const float* __restrict__ lpart,
        bf16* __restrict__ Z) {
    const int qb = blockIdx.x;
    const int bh = blockIdx.y;
    if (qb < 4) return;
    const int g = qb >> 2;
    const int nch = g + 1;
    const int wbase = 2 * g * (g + 1) + (qb & 3) * (g + 1);
    const int slot0 = bh * 144 + wbase;

    const int tid = threadIdx.x;
    const int r   = tid >> 2;
    const int cs  = tid & 3;

    float l = 0.0f;
    for (int c = 0; c < nch; ++c)
        l += lpart[(size_t)(slot0 + c) * 64 + r];
    const float rinv = 1.0f / l;

    const int b = bh / Hq, h = bh % Hq;
    const int s = qb * 64 + r;
    bf16* zrow = Z + (size_t)(b * Sq + s) * Eq + h * Dq;

#pragma unroll
    for (int seg = 0; seg < 8; ++seg) {
        int col0 = cs * 64 + seg * 8;
        float acc[8] = {};
        for (int c = 0; c < nch; ++c) {
            bf16x8 v = *(const bf16x8*)&Opart[(size_t)(slot0 + c) * (64 * 256) + r * 256 + col0];
#pragma unroll
            for (int i = 0; i < 8; ++i) {
                short sv = v[i];
                acc[i] += bf2f(sv);
            }
        }
        bf16x8 outv;
#pragma unroll
        for (int i = 0; i < 8; ++i) outv[i] = f2bf(acc[i] * rinv);
        *(bf16x8*)&zrow[col0] = outv;
    }
}

// ---------------------------------------------------------------------------
// Output projection (R1 structure: double-buffered BK=32, one barrier/step).
// ---------------------------------------------------------------------------
__global__ __launch_bounds__(256) void outproj_kernel(
        const bf16* __restrict__ Z, const bf16* __restrict__ Wot,
        const float* __restrict__ bo, float* __restrict__ out) {
    const int x   = blockIdx.x;
    const int xcd = x & 7;
    const int kk0 = x >> 3;               // [0,48)
    const int mt  = xcd * 8 + (kk0 / 6);  // [0,64)
    const int nt  = kk0 % 6;              // [0,6)

    __shared__ bf16 As[2][128 * 32];
    __shared__ bf16 Bs[2][128 * 32];

    const int tid  = threadIdx.x;
    const int lane = tid & 63;
    const int w    = tid >> 6;
    const int quad = lane >> 4;
    const int l16  = lane & 15;
    const int wm   = (w & 1) * 64;
    const int wn   = (w >> 1) * 64;

    const int m0 = mt * 128;
    const int n0 = nt * 128;

    int srow[2], skc[2];
#pragma unroll
    for (int i = 0; i < 2; ++i) {
        int ci  = (w * 2 + i) * 64 + lane;
        srow[i] = ci >> 2;
        skc[i]  = (ci & 3) ^ ((srow[i] >> 1) & 3);
    }

#define STAGE2(buf, k0)                                                       \
    {                                                                         \
        _Pragma("unroll")                                                     \
        for (int i = 0; i < 2; ++i) {                                         \
            gl2lds16(&Z[(size_t)(m0 + srow[i]) * Eq + (k0) + skc[i] * 8],     \
                     &As[buf][(w * 2 + i) * 512]);                            \
            gl2lds16(&Wot[(size_t)(n0 + srow[i]) * Eq + (k0) + skc[i] * 8],   \
                     &Bs[buf][(w * 2 + i) * 512]);                            \
        }                                                                     \
    }

    STAGE2(0, 0);
    __syncthreads();

    f32x4 acc[4][4] = {};

    for (int s = 0; s < 24; ++s) {
        if (s + 1 < 24) STAGE2((s + 1) & 1, (s + 1) * 32);
        const bf16* A  = As[s & 1];
        const bf16* Bv = Bs[s & 1];
        bf16x8 af[4], bfr[4];
#pragma unroll
        for (int mi = 0; mi < 4; ++mi) {
            int row = wm + mi * 16 + l16;
            int c   = quad ^ ((row >> 1) & 3);
            af[mi]  = *(const bf16x8*)&A[row * 32 + c * 8];
        }
#pragma unroll
        for (int ni = 0; ni < 4; ++ni) {
            int row = wn + ni * 16 + l16;
            int c   = quad ^ ((row >> 1) & 3);
            bfr[ni] = *(const bf16x8*)&Bv[row * 32 + c * 8];
        }
#pragma unroll
        for (int mi = 0; mi < 4; ++mi)
#pragma unroll
            for (int ni = 0; ni < 4; ++ni)
                acc[mi][ni] = mfma16(af[mi], bfr[ni], acc[mi][ni]);
        __syncthreads();
    }
#undef STAGE2

#pragma unroll
    for (int ni = 0; ni < 4; ++ni) {
        int n = n0 + wn + ni * 16 + l16;
        float bias = bo[n];
#pragma unroll
        for (int mi = 0; mi < 4; ++mi) {
#pragma unroll
            for (int r = 0; r < 4; ++r) {
                int m = m0 + wm + mi * 16 + quad * 4 + r;
                out[(size_t)m * Eq + n] = acc[mi][ni][r] + bias;
            }
        }
    }
}

// ---------------------------------------------------------------------------
extern "C" void kernel_launch(void* const* d_in, const int* in_sizes, int n_in,
                              void* d_out, int out_size, void* d_ws, size_t ws_size,
                              hipStream_t stream) {
    const float* Xk = (const float*)d_in[0];
    const float* Xv = (const float*)d_in[1];
    const float* Xq = (const float*)d_in[2];
    const float* WK = (const float*)d_in[3];
    const float* WV = (const float*)d_in[4];
    const float* WQ = (const float*)d_in[5];
    const float* Wo = (const float*)d_in[6];
    const float* bo = (const float*)d_in[7];
    float* out = (float*)d_out;

    // workspace layout (bf16 elements)
    bf16* ws = (bf16*)d_ws;
    const size_t WSZ  = (size_t)Hq * Eq * Dq;   // 589824
    const size_t QKV  = (size_t)BHq * Sq * Dq;  // 6291456
    bf16* WtK = ws;                 // [t][h][d][e], t=0 K /1 V /2 Q
    bf16* WtO = WtK + 3 * WSZ;      // [out_e][in_e]
    bf16* Qp  = WtO + (size_t)Eq * Eq;
    bf16* Kp  = Qp + QKV;           // [b,h,s,d]
    bf16* Vt  = Kp + QKV;           // [b,h,d,s]
    bf16* Zb  = Vt + QKV;           // [b,s,e]
    bf16* Opart = Zb + QKV;         // 1728 x 64 x 256 bf16
    float* lpart = (float*)(Opart + (size_t)1728 * 64 * 256);
    // Xb aliases Opart: proj reads Xb before attn writes Opart (stream order).
    bf16* Xb = Opart;

    prep_kernel<<<11520, 256, 0, stream>>>(Xk, Xv, Xq, Xb, WK, WV, WQ, Wo, WtK, WtO);
    proj_kernel<<<dim3(384, 3), 256, 0, stream>>>(Xb, WtK, Kp, Vt, Qp);
    attn_kernel<<<1728, 256, 0, stream>>>(Qp, Kp, Vt, Zb, Opart, lpart);
    combine_kernel<<<dim3(32, BHq), 256, 0, stream>>>(Opart, lpart, Zb);
    outproj_kernel<<<384, 256, 0, stream>>>(Zb, WtO, bo, out);
}

// Round 9
// 274.135 us; speedup vs baseline: 1.4875x; 1.1632x over previous
//
#include <hip/hip_runtime.h>
#include <hip/hip_bf16.h>

// Problem dims (fixed)
#define Bq 4
#define Sq 2048
#define Eq 768
#define Hq 3
#define Dq 256
#define BHq (Bq*Hq)

typedef __hip_bfloat16 bf16;
typedef __attribute__((ext_vector_type(8))) short bf16x8;
typedef __attribute__((ext_vector_type(4))) float f32x4;

__device__ __forceinline__ f32x4 mfma16(bf16x8 a, bf16x8 b, f32x4 c) {
    return __builtin_amdgcn_mfma_f32_16x16x32_bf16(a, b, c, 0, 0, 0);
}

__device__ __forceinline__ short f2bf(float x) {
    bf16 b = __float2bfloat16(x);
    return *(short*)&b;
}

__device__ __forceinline__ float bf2f(short s) {
    bf16 b = *reinterpret_cast<bf16*>(&s);
    return __bfloat162float(b);
}

__device__ __forceinline__ bf16x8 cvt8(float4 a, float4 b) {
    bf16x8 r;
    r[0] = f2bf(a.x); r[1] = f2bf(a.y); r[2] = f2bf(a.z); r[3] = f2bf(a.w);
    r[4] = f2bf(b.x); r[5] = f2bf(b.y); r[6] = f2bf(b.z); r[7] = f2bf(b.w);
    return r;
}

// async global->LDS, 16B per lane; LDS dest = wave-uniform base + lane*16
__device__ __forceinline__ void gl2lds16(const bf16* g, bf16* l) {
    __builtin_amdgcn_global_load_lds(
        (const __attribute__((address_space(1))) unsigned int*)g,
        (__attribute__((address_space(3))) unsigned int*)l,
        16, 0, 0);
}

// ---------------------------------------------------------------------------
// Fused prep: X f32->bf16 convert (blocks [0,9216)) + weight transposes
// (blocks [9216,11520)). All blocks 256 threads.
// ---------------------------------------------------------------------------
__global__ __launch_bounds__(256) void prep_kernel(
        const float* __restrict__ Xk, const float* __restrict__ Xv,
        const float* __restrict__ Xq, bf16* __restrict__ Xb,
        const float* __restrict__ WK, const float* __restrict__ WV,
        const float* __restrict__ WQ, const float* __restrict__ Wo,
        bf16* __restrict__ WtK, bf16* __restrict__ Wot) {
    const int blk = blockIdx.x;
    const int tid = threadIdx.x;

    if (blk < 9216) {   // convert
        const int t = blk / 3072;
        const int i = blk % 3072;
        const float* X = (t == 0) ? Xk : (t == 1) ? Xv : Xq;
        size_t idx = ((size_t)i * 256 + tid) * 8;
        float4 a = *(const float4*)&X[idx];
        float4 b = *(const float4*)&X[idx + 4];
        *(bf16x8*)&Xb[(size_t)t * ((size_t)Bq * Sq * Eq) + idx] = cvt8(a, b);
        return;
    }

    __shared__ float tile[32][33];
    const float* in;
    bf16* out;
    int R, C, bx, by;
    if (blk < 10944) {            // QKV weight transposes
        int r  = blk - 9216;      // [0,1728)
        int t  = r / 576;
        int rr = r % 576;
        int batch = rr / 192;
        int tl = rr % 192;
        bx = tl & 7; by = tl >> 3;
        R = Eq; C = Dq;
        const float* Wsrc = (t == 0) ? WK : (t == 1) ? WV : WQ;
        in  = Wsrc + (size_t)batch * R * C;
        out = WtK + (size_t)t * ((size_t)Hq * Eq * Dq) + (size_t)batch * R * C;
    } else {                      // Wo transpose
        int rr = blk - 10944;     // [0,576)
        bx = rr % 24; by = rr / 24;
        R = Eq; C = Eq;
        in  = Wo;
        out = Wot;
    }
    const int tx = tid & 31;
    const int ty = tid >> 5;
#pragma unroll
    for (int i = ty; i < 32; i += 8)
        tile[i][tx] = in[(size_t)(by * 32 + i) * C + bx * 32 + tx];
    __syncthreads();
#pragma unroll
    for (int i = ty; i < 32; i += 8)
        out[(size_t)(bx * 32 + i) * R + by * 32 + tx] = __float2bfloat16(tile[tx][i]);
}

// ---------------------------------------------------------------------------
// Projection GEMM (R3 version: BK=32 double-buffer + coalesced LDS epilogue).
// ---------------------------------------------------------------------------
__global__ __launch_bounds__(256) void proj_kernel(
        const bf16* __restrict__ Xb, const bf16* __restrict__ Wt,
        bf16* __restrict__ Kp, bf16* __restrict__ Vt, bf16* __restrict__ Qp) {
    const int sel = blockIdx.y;
    const int x   = blockIdx.x;
    const int xcd = x & 7;
    const int kk0 = x >> 3;               // [0,48)
    const int mt  = xcd * 8 + (kk0 / 6);  // [0,64)
    const int nt  = kk0 % 6;              // [0,6)
    const bf16* X = Xb + (size_t)sel * ((size_t)Bq * Sq * Eq);
    const bf16* W = Wt + (size_t)sel * ((size_t)Hq * Eq * Dq);

    __shared__ struct {
        bf16 A[2][128 * 32];
        bf16 B[2][128 * 32];
    } sm;
    auto& As = sm.A;
    auto& Bs = sm.B;

    const int tid  = threadIdx.x;
    const int lane = tid & 63;
    const int w    = tid >> 6;
    const int quad = lane >> 4;
    const int l16  = lane & 15;
    const int wm   = (w & 1) * 64;
    const int wn   = (w >> 1) * 64;

    const int m0 = mt * 128;
    const int n0 = nt * 128;

    int srow[2], skc[2];
#pragma unroll
    for (int i = 0; i < 2; ++i) {
        int ci  = (w * 2 + i) * 64 + lane;      // [0,512) chunk-of-8 index
        srow[i] = ci >> 2;                      // [0,128)
        skc[i]  = (ci & 3) ^ ((srow[i] >> 1) & 3);
    }

#define STAGE(buf, k0)                                                        \
    {                                                                         \
        _Pragma("unroll")                                                     \
        for (int i = 0; i < 2; ++i) {                                         \
            gl2lds16(&X[(size_t)(m0 + srow[i]) * Eq + (k0) + skc[i] * 8],     \
                     &As[buf][(w * 2 + i) * 512]);                            \
            gl2lds16(&W[(size_t)(n0 + srow[i]) * Eq + (k0) + skc[i] * 8],     \
                     &Bs[buf][(w * 2 + i) * 512]);                            \
        }                                                                     \
    }

    STAGE(0, 0);
    __syncthreads();

    f32x4 acc[4][4] = {};

    for (int s = 0; s < 24; ++s) {
        if (s + 1 < 24) STAGE((s + 1) & 1, (s + 1) * 32);
        const bf16* A  = As[s & 1];
        const bf16* Bv = Bs[s & 1];
        bf16x8 af[4], bfr[4];
#pragma unroll
        for (int mi = 0; mi < 4; ++mi) {
            int row = wm + mi * 16 + l16;
            int c   = quad ^ ((row >> 1) & 3);
            af[mi]  = *(const bf16x8*)&A[row * 32 + c * 8];
        }
#pragma unroll
        for (int ni = 0; ni < 4; ++ni) {
            int row = wn + ni * 16 + l16;
            int c   = quad ^ ((row >> 1) & 3);
            bfr[ni] = *(const bf16x8*)&Bv[row * 32 + c * 8];
        }
#pragma unroll
        for (int mi = 0; mi < 4; ++mi)
#pragma unroll
            for (int ni = 0; ni < 4; ++ni)
                acc[mi][ni] = mfma16(af[mi], bfr[ni], acc[mi][ni]);
        __syncthreads();
    }
#undef STAGE

    // epilogue: restage C-tile in LDS, then coalesced 256B-row stores
    bf16* ct = (bf16*)&sm;           // 128x128 bf16 = 32KB
    const int b  = m0 / Sq;
    const int s0 = m0 % Sq;
    const int h  = n0 >> 8;
    const int d0 = n0 & 255;
    const int bh = b * Hq + h;

    if (sel == 1) {
#pragma unroll
        for (int mi = 0; mi < 4; ++mi)
#pragma unroll
            for (int ni = 0; ni < 4; ++ni)
#pragma unroll
                for (int r = 0; r < 4; ++r) {
                    int row = wn + ni * 16 + l16;           // d_local
                    int col = wm + mi * 16 + quad * 4 + r;  // s_local
                    ct[row * 128 + (((col >> 3) ^ (row & 15)) * 8) + (col & 7)] =
                        __float2bfloat16(acc[mi][ni][r]);
                }
    } else {
#pragma unroll
        for (int mi = 0; mi < 4; ++mi)
#pragma unroll
            for (int ni = 0; ni < 4; ++ni)
#pragma unroll
                for (int r = 0; r < 4; ++r) {
                    int row = wm + mi * 16 + quad * 4 + r;  // s_local
                    int col = wn + ni * 16 + l16;           // n_local
                    ct[row * 128 + (((col >> 3) ^ (row & 15)) * 8) + (col & 7)] =
                        __float2bfloat16(acc[mi][ni][r]);
                }
    }
    __syncthreads();
    {
        const int rr = tid >> 4;   // 0..15
        const int c  = tid & 15;   // 0..15
#pragma unroll
        for (int p = 0; p < 8; ++p) {
            int r  = p * 16 + rr;
            int cp = c ^ (r & 15);
            bf16x8 v = *(const bf16x8*)&ct[r * 128 + cp * 8];
            if (sel == 1)
                *(bf16x8*)&Vt[(size_t)(bh * Dq + d0 + r) * Sq + s0 + c * 8] = v;
            else if (sel == 0)
                *(bf16x8*)&Kp[(size_t)(bh * Sq + s0 + r) * Dq + d0 + c * 8] = v;
            else
                *(bf16x8*)&Qp[(size_t)(bh * Sq + s0 + r) * Dq + d0 + c * 8] = v;
        }
    }
}

// ---------------------------------------------------------------------------
// Split-K flash attention — R8 kernel body EXACTLY (65.0us measured), with
// ONLY the work-distribution indexing changed: chunk size 4 -> 8 tiles.
// Slots/bh 144 -> 80, grid 1728 -> 960 (= 8 XCDs x 120), singles qb<8.
// Group g8 = qb>>3 has g8+1 chunks of 8 tiles; slot base = 4*g8*(g8+1).
// Inner per-tile code, LDS layout, register profile untouched.
// ---------------------------------------------------------------------------
__global__ __launch_bounds__(256, 2) void attn_kernel(
        const bf16* __restrict__ Qp, const bf16* __restrict__ Kp,
        const bf16* __restrict__ Vt, bf16* __restrict__ Z,
        bf16* __restrict__ Opart, float* __restrict__ lpart) {
    __shared__ bf16 Ks[64 * 256];
    __shared__ bf16 Vs[256 * 64];
    __shared__ bf16 Pl[4 * 16 * 64];

    const float SCALE = 0.022097086912079608f;  // 1/sqrt(2048)

    const int id    = blockIdx.x;     // [0,960)
    const int lane8 = id & 7;         // XCD
    const int j     = id >> 3;        // [0,120)
    const int W     = lane8 * 120 + j;
    const int bh    = W / 80;
    const int w80   = W % 80;
    int g8 = 0;                       // group bases: 0, 8, 24, 48
    if (w80 >= 8)  g8 = 1;
    if (w80 >= 24) g8 = 2;
    if (w80 >= 48) g8 = 3;
    const int rem   = w80 - 4 * g8 * (g8 + 1);
    const int qb    = g8 * 8 + rem / (g8 + 1);
    const int chunk = rem % (g8 + 1);
    const int t0    = chunk * 8;
    const int t1    = min(t0 + 8, qb + 1);
    const bool single = (qb < 8);

    const int tid  = threadIdx.x;
    const int lane = tid & 63;
    const int w    = tid >> 6;
    const int quad = lane >> 4;
    const int l16  = lane & 15;
    const int q0   = qb * 64 + w * 16;

    bf16x8 qf[8];
    {
        const bf16* Qbase = Qp + (size_t)(bh * Sq + q0 + l16) * Dq;
#pragma unroll
        for (int c = 0; c < 8; ++c)
            qf[c] = *(const bf16x8*)&Qbase[c * 32 + quad * 8];
    }

    const bf16* Kbh = Kp + (size_t)bh * Sq * Dq;
    const bf16* Vbh = Vt + (size_t)bh * Dq * Sq;

    f32x4 o[16] = {};
    float lsum[4] = {0.0f, 0.0f, 0.0f, 0.0f};

    for (int t = t0; t < t1; ++t) {
        const int k0 = t * 64;

        bf16x8 kreg[8], vreg[8];
#pragma unroll
        for (int p = 0; p < 8; ++p) {
            int c = p * 256 + tid;
            int row = c >> 5, cc = c & 31;
            kreg[p] = *(const bf16x8*)&Kbh[(size_t)(k0 + row) * Dq + cc * 8];
        }
#pragma unroll
        for (int p = 0; p < 8; ++p) {
            int c = p * 256 + tid;
            int row = c >> 3, cc = c & 7;
            vreg[p] = *(const bf16x8*)&Vbh[(size_t)row * Sq + k0 + cc * 8];
        }

        __syncthreads();
#pragma unroll
        for (int p = 0; p < 8; ++p) {
            int c = p * 256 + tid;
            int row = c >> 5, cc = c & 31;
            *(bf16x8*)&Ks[row * 256 + (cc ^ (row & 7)) * 8] = kreg[p];
        }
#pragma unroll
        for (int p = 0; p < 8; ++p) {
            int c = p * 256 + tid;
            int row = c >> 3, cc = c & 7;
            *(bf16x8*)&Vs[row * 64 + (cc ^ (row & 7)) * 8] = vreg[p];
        }
        __syncthreads();

        f32x4 sf[4] = {};
        __builtin_amdgcn_s_setprio(1);
#pragma unroll
        for (int c = 0; c < 8; ++c) {
            int cc = c * 4 + quad;
#pragma unroll
            for (int ni = 0; ni < 4; ++ni) {
                int key = ni * 16 + l16;
                bf16x8 kf = *(const bf16x8*)&Ks[key * 256 + (cc ^ (key & 7)) * 8];
                sf[ni] = mfma16(qf[c], kf, sf[ni]);
            }
        }
        __builtin_amdgcn_s_setprio(0);

        const bool diag = (t == qb);
#pragma unroll
        for (int ni = 0; ni < 4; ++ni) {
#pragma unroll
            for (int r = 0; r < 4; ++r) {
                float p = __expf(sf[ni][r] * SCALE);
                if (diag) {
                    int kg = k0 + ni * 16 + l16;
                    int qg = q0 + quad * 4 + r;
                    if (kg > qg) p = 0.0f;
                }
                lsum[r] += p;
                int row = quad * 4 + r;
                int col = ni * 16 + l16;
                int cc  = col >> 3;
                Pl[w * 1024 + row * 64 + (cc ^ (row & 7)) * 8 + (col & 7)] =
                    __float2bfloat16(p);
            }
        }

        __builtin_amdgcn_s_setprio(1);
#pragma unroll
        for (int c2 = 0; c2 < 2; ++c2) {
            int cc = c2 * 4 + quad;
            bf16x8 af = *(const bf16x8*)&Pl[w * 1024 + l16 * 64 + (cc ^ (l16 & 7)) * 8];
#pragma unroll
            for (int ni = 0; ni < 16; ++ni) {
                int d = ni * 16 + l16;
                bf16x8 vf = *(const bf16x8*)&Vs[d * 64 + (cc ^ (d & 7)) * 8];
                o[ni] = mfma16(af, vf, o[ni]);
            }
        }
        __builtin_amdgcn_s_setprio(0);
    }

#pragma unroll
    for (int off = 1; off < 16; off <<= 1)
#pragma unroll
        for (int r = 0; r < 4; ++r)
            lsum[r] += __shfl_xor(lsum[r], off);

    if (single) {
        const int b = bh / Hq, h = bh % Hq;
        float rinv[4];
#pragma unroll
        for (int r = 0; r < 4; ++r) rinv[r] = 1.0f / lsum[r];
#pragma unroll
        for (int ni = 0; ni < 16; ++ni) {
#pragma unroll
            for (int r = 0; r < 4; ++r) {
                int s = q0 + quad * 4 + r;
                int e = h * Dq + ni * 16 + l16;
                Z[(size_t)(b * Sq + s) * Eq + e] = __float2bfloat16(o[ni][r] * rinv[r]);
            }
        }
    } else {
        const int slot = bh * 80 + w80;
        bf16* Ob = Opart + (size_t)slot * (64 * 256);
#pragma unroll
        for (int ni = 0; ni < 16; ++ni) {
#pragma unroll
            for (int r = 0; r < 4; ++r) {
                int row = w * 16 + quad * 4 + r;
                int col = ni * 16 + l16;
                Ob[row * 256 + col] = __float2bfloat16(o[ni][r]);
            }
        }
        if (l16 == 0) {
#pragma unroll
            for (int r = 0; r < 4; ++r)
                lpart[(size_t)slot * 64 + w * 16 + quad * 4 + r] = lsum[r];
        }
    }
}

// ---------------------------------------------------------------------------
// Combine partials (chunk=8 indexing). Grid (32, 12); qb < 8 skipped.
// ---------------------------------------------------------------------------
__global__ __launch_bounds__(256) void combine_kernel(
        const bf16* __restrict__ Opart, const float* __restrict__ lpart,
        bf16* __restrict__ Z) {
    const int qb = blockIdx.x;
    const int bh = blockIdx.y;
    if (qb < 8) return;
    const int g8 = qb >> 3;
    const int nch = g8 + 1;
    const int slot0 = bh * 80 + 4 * g8 * (g8 + 1) + (qb - g8 * 8) * (g8 + 1);

    const int tid = threadIdx.x;
    const int r   = tid >> 2;
    const int cs  = tid & 3;

    float l = 0.0f;
    for (int c = 0; c < nch; ++c)
        l += lpart[(size_t)(slot0 + c) * 64 + r];
    const float rinv = 1.0f / l;

    const int b = bh / Hq, h = bh % Hq;
    const int s = qb * 64 + r;
    bf16* zrow = Z + (size_t)(b * Sq + s) * Eq + h * Dq;

#pragma unroll
    for (int seg = 0; seg < 8; ++seg) {
        int col0 = cs * 64 + seg * 8;
        float acc[8] = {};
        for (int c = 0; c < nch; ++c) {
            bf16x8 v = *(const bf16x8*)&Opart[(size_t)(slot0 + c) * (64 * 256) + r * 256 + col0];
#pragma unroll
            for (int i = 0; i < 8; ++i) {
                short sv = v[i];
                acc[i] += bf2f(sv);
            }
        }
        bf16x8 outv;
#pragma unroll
        for (int i = 0; i < 8; ++i) outv[i] = f2bf(acc[i] * rinv);
        *(bf16x8*)&zrow[col0] = outv;
    }
}

// ---------------------------------------------------------------------------
// Output projection (R1 structure: double-buffered BK=32, one barrier/step).
// ---------------------------------------------------------------------------
__global__ __launch_bounds__(256) void outproj_kernel(
        const bf16* __restrict__ Z, const bf16* __restrict__ Wot,
        const float* __restrict__ bo, float* __restrict__ out) {
    const int x   = blockIdx.x;
    const int xcd = x & 7;
    const int kk0 = x >> 3;               // [0,48)
    const int mt  = xcd * 8 + (kk0 / 6);  // [0,64)
    const int nt  = kk0 % 6;              // [0,6)

    __shared__ bf16 As[2][128 * 32];
    __shared__ bf16 Bs[2][128 * 32];

    const int tid  = threadIdx.x;
    const int lane = tid & 63;
    const int w    = tid >> 6;
    const int quad = lane >> 4;
    const int l16  = lane & 15;
    const int wm   = (w & 1) * 64;
    const int wn   = (w >> 1) * 64;

    const int m0 = mt * 128;
    const int n0 = nt * 128;

    int srow[2], skc[2];
#pragma unroll
    for (int i = 0; i < 2; ++i) {
        int ci  = (w * 2 + i) * 64 + lane;
        srow[i] = ci >> 2;
        skc[i]  = (ci & 3) ^ ((srow[i] >> 1) & 3);
    }

#define STAGE2(buf, k0)                                                       \
    {                                                                         \
        _Pragma("unroll")                                                     \
        for (int i = 0; i < 2; ++i) {                                         \
            gl2lds16(&Z[(size_t)(m0 + srow[i]) * Eq + (k0) + skc[i] * 8],     \
                     &As[buf][(w * 2 + i) * 512]);                            \
            gl2lds16(&Wot[(size_t)(n0 + srow[i]) * Eq + (k0) + skc[i] * 8],   \
                     &Bs[buf][(w * 2 + i) * 512]);                            \
        }                                                                     \
    }

    STAGE2(0, 0);
    __syncthreads();

    f32x4 acc[4][4] = {};

    for (int s = 0; s < 24; ++s) {
        if (s + 1 < 24) STAGE2((s + 1) & 1, (s + 1) * 32);
        const bf16* A  = As[s & 1];
        const bf16* Bv = Bs[s & 1];
        bf16x8 af[4], bfr[4];
#pragma unroll
        for (int mi = 0; mi < 4; ++mi) {
            int row = wm + mi * 16 + l16;
            int c   = quad ^ ((row >> 1) & 3);
            af[mi]  = *(const bf16x8*)&A[row * 32 + c * 8];
        }
#pragma unroll
        for (int ni = 0; ni < 4; ++ni) {
            int row = wn + ni * 16 + l16;
            int c   = quad ^ ((row >> 1) & 3);
            bfr[ni] = *(const bf16x8*)&Bv[row * 32 + c * 8];
        }
#pragma unroll
        for (int mi = 0; mi < 4; ++mi)
#pragma unroll
            for (int ni = 0; ni < 4; ++ni)
                acc[mi][ni] = mfma16(af[mi], bfr[ni], acc[mi][ni]);
        __syncthreads();
    }
#undef STAGE2

#pragma unroll
    for (int ni = 0; ni < 4; ++ni) {
        int n = n0 + wn + ni * 16 + l16;
        float bias = bo[n];
#pragma unroll
        for (int mi = 0; mi < 4; ++mi) {
#pragma unroll
            for (int r = 0; r < 4; ++r) {
                int m = m0 + wm + mi * 16 + quad * 4 + r;
                out[(size_t)m * Eq + n] = acc[mi][ni][r] + bias;
            }
        }
    }
}

// ---------------------------------------------------------------------------
extern "C" void kernel_launch(void* const* d_in, const int* in_sizes, int n_in,
                              void* d_out, int out_size, void* d_ws, size_t ws_size,
                              hipStream_t stream) {
    const float* Xk = (const float*)d_in[0];
    const float* Xv = (const float*)d_in[1];
    const float* Xq = (const float*)d_in[2];
    const float* WK = (const float*)d_in[3];
    const float* WV = (const float*)d_in[4];
    const float* WQ = (const float*)d_in[5];
    const float* Wo = (const float*)d_in[6];
    const float* bo = (const float*)d_in[7];
    float* out = (float*)d_out;

    // workspace layout (bf16 elements)
    bf16* ws = (bf16*)d_ws;
    const size_t WSZ  = (size_t)Hq * Eq * Dq;   // 589824
    const size_t QKV  = (size_t)BHq * Sq * Dq;  // 6291456
    bf16* WtK = ws;                 // [t][h][d][e], t=0 K /1 V /2 Q
    bf16* WtO = WtK + 3 * WSZ;      // [out_e][in_e]
    bf16* Qp  = WtO + (size_t)Eq * Eq;
    bf16* Kp  = Qp + QKV;           // [b,h,s,d]
    bf16* Vt  = Kp + QKV;           // [b,h,d,s]
    bf16* Zb  = Vt + QKV;           // [b,s,e]
    bf16* Opart = Zb + QKV;         // 960 x 64 x 256 bf16 (31.5 MB)
    // Xb aliases Opart (proj reads Xb before attn writes Opart). Xb spans
    // 3*B*S*E = 37.75 MB > Opart, so lpart is placed after the Xb span.
    bf16* Xb = Opart;
    float* lpart = (float*)(Opart + (size_t)3 * Bq * Sq * Eq);

    prep_kernel<<<11520, 256, 0, stream>>>(Xk, Xv, Xq, Xb, WK, WV, WQ, Wo, WtK, WtO);
    proj_kernel<<<dim3(384, 3), 256, 0, stream>>>(Xb, WtK, Kp, Vt, Qp);
    attn_kernel<<<960, 256, 0, stream>>>(Qp, Kp, Vt, Zb, Opart, lpart);
    combine_kernel<<<dim3(32, BHq), 256, 0, stream>>>(Opart, lpart, Zb);
    outproj_kernel<<<384, 256, 0, stream>>>(Zb, WtO, bo, out);
}

// Round 10
// 272.517 us; speedup vs baseline: 1.4964x; 1.0059x over previous
//
#include <hip/hip_runtime.h>
#include <hip/hip_bf16.h>

// Problem dims (fixed)
#define Bq 4
#define Sq 2048
#define Eq 768
#define Hq 3
#define Dq 256
#define BHq (Bq*Hq)

typedef __hip_bfloat16 bf16;
typedef __attribute__((ext_vector_type(8))) short bf16x8;
typedef __attribute__((ext_vector_type(4))) float f32x4;

__device__ __forceinline__ f32x4 mfma16(bf16x8 a, bf16x8 b, f32x4 c) {
    return __builtin_amdgcn_mfma_f32_16x16x32_bf16(a, b, c, 0, 0, 0);
}

__device__ __forceinline__ short f2bf(float x) {
    bf16 b = __float2bfloat16(x);
    return *(short*)&b;
}

__device__ __forceinline__ float bf2f(short s) {
    bf16 b = *reinterpret_cast<bf16*>(&s);
    return __bfloat162float(b);
}

__device__ __forceinline__ bf16x8 cvt8(float4 a, float4 b) {
    bf16x8 r;
    r[0] = f2bf(a.x); r[1] = f2bf(a.y); r[2] = f2bf(a.z); r[3] = f2bf(a.w);
    r[4] = f2bf(b.x); r[5] = f2bf(b.y); r[6] = f2bf(b.z); r[7] = f2bf(b.w);
    return r;
}

// async global->LDS, 16B per lane; LDS dest = wave-uniform base + lane*16
__device__ __forceinline__ void gl2lds16(const bf16* g, bf16* l) {
    __builtin_amdgcn_global_load_lds(
        (const __attribute__((address_space(1))) unsigned int*)g,
        (__attribute__((address_space(3))) unsigned int*)l,
        16, 0, 0);
}

// ---------------------------------------------------------------------------
// Fused prep: X f32->bf16 convert (blocks [0,9216)) + weight transposes
// (blocks [9216,11520)). All blocks 256 threads.
// ---------------------------------------------------------------------------
__global__ __launch_bounds__(256) void prep_kernel(
        const float* __restrict__ Xk, const float* __restrict__ Xv,
        const float* __restrict__ Xq, bf16* __restrict__ Xb,
        const float* __restrict__ WK, const float* __restrict__ WV,
        const float* __restrict__ WQ, const float* __restrict__ Wo,
        bf16* __restrict__ WtK, bf16* __restrict__ Wot) {
    const int blk = blockIdx.x;
    const int tid = threadIdx.x;

    if (blk < 9216) {   // convert
        const int t = blk / 3072;
        const int i = blk % 3072;
        const float* X = (t == 0) ? Xk : (t == 1) ? Xv : Xq;
        size_t idx = ((size_t)i * 256 + tid) * 8;
        float4 a = *(const float4*)&X[idx];
        float4 b = *(const float4*)&X[idx + 4];
        *(bf16x8*)&Xb[(size_t)t * ((size_t)Bq * Sq * Eq) + idx] = cvt8(a, b);
        return;
    }

    __shared__ float tile[32][33];
    const float* in;
    bf16* out;
    int R, C, bx, by;
    if (blk < 10944) {            // QKV weight transposes
        int r  = blk - 9216;      // [0,1728)
        int t  = r / 576;
        int rr = r % 576;
        int batch = rr / 192;
        int tl = rr % 192;
        bx = tl & 7; by = tl >> 3;
        R = Eq; C = Dq;
        const float* Wsrc = (t == 0) ? WK : (t == 1) ? WV : WQ;
        in  = Wsrc + (size_t)batch * R * C;
        out = WtK + (size_t)t * ((size_t)Hq * Eq * Dq) + (size_t)batch * R * C;
    } else {                      // Wo transpose
        int rr = blk - 10944;     // [0,576)
        bx = rr % 24; by = rr / 24;
        R = Eq; C = Eq;
        in  = Wo;
        out = Wot;
    }
    const int tx = tid & 31;
    const int ty = tid >> 5;
#pragma unroll
    for (int i = ty; i < 32; i += 8)
        tile[i][tx] = in[(size_t)(by * 32 + i) * C + bx * 32 + tx];
    __syncthreads();
#pragma unroll
    for (int i = ty; i < 32; i += 8)
        out[(size_t)(bx * 32 + i) * R + by * 32 + tx] = __float2bfloat16(tile[tx][i]);
}

// ---------------------------------------------------------------------------
// Projection GEMM (R3 version: BK=32 double-buffer + coalesced LDS epilogue).
// ---------------------------------------------------------------------------
__global__ __launch_bounds__(256) void proj_kernel(
        const bf16* __restrict__ Xb, const bf16* __restrict__ Wt,
        bf16* __restrict__ Kp, bf16* __restrict__ Vt, bf16* __restrict__ Qp) {
    const int sel = blockIdx.y;
    const int x   = blockIdx.x;
    const int xcd = x & 7;
    const int kk0 = x >> 3;               // [0,48)
    const int mt  = xcd * 8 + (kk0 / 6);  // [0,64)
    const int nt  = kk0 % 6;              // [0,6)
    const bf16* X = Xb + (size_t)sel * ((size_t)Bq * Sq * Eq);
    const bf16* W = Wt + (size_t)sel * ((size_t)Hq * Eq * Dq);

    __shared__ struct {
        bf16 A[2][128 * 32];
        bf16 B[2][128 * 32];
    } sm;
    auto& As = sm.A;
    auto& Bs = sm.B;

    const int tid  = threadIdx.x;
    const int lane = tid & 63;
    const int w    = tid >> 6;
    const int quad = lane >> 4;
    const int l16  = lane & 15;
    const int wm   = (w & 1) * 64;
    const int wn   = (w >> 1) * 64;

    const int m0 = mt * 128;
    const int n0 = nt * 128;

    int srow[2], skc[2];
#pragma unroll
    for (int i = 0; i < 2; ++i) {
        int ci  = (w * 2 + i) * 64 + lane;      // [0,512) chunk-of-8 index
        srow[i] = ci >> 2;                      // [0,128)
        skc[i]  = (ci & 3) ^ ((srow[i] >> 1) & 3);
    }

#define STAGE(buf, k0)                                                        \
    {                                                                         \
        _Pragma("unroll")                                                     \
        for (int i = 0; i < 2; ++i) {                                         \
            gl2lds16(&X[(size_t)(m0 + srow[i]) * Eq + (k0) + skc[i] * 8],     \
                     &As[buf][(w * 2 + i) * 512]);                            \
            gl2lds16(&W[(size_t)(n0 + srow[i]) * Eq + (k0) + skc[i] * 8],     \
                     &Bs[buf][(w * 2 + i) * 512]);                            \
        }                                                                     \
    }

    STAGE(0, 0);
    __syncthreads();

    f32x4 acc[4][4] = {};

    for (int s = 0; s < 24; ++s) {
        if (s + 1 < 24) STAGE((s + 1) & 1, (s + 1) * 32);
        const bf16* A  = As[s & 1];
        const bf16* Bv = Bs[s & 1];
        bf16x8 af[4], bfr[4];
#pragma unroll
        for (int mi = 0; mi < 4; ++mi) {
            int row = wm + mi * 16 + l16;
            int c   = quad ^ ((row >> 1) & 3);
            af[mi]  = *(const bf16x8*)&A[row * 32 + c * 8];
        }
#pragma unroll
        for (int ni = 0; ni < 4; ++ni) {
            int row = wn + ni * 16 + l16;
            int c   = quad ^ ((row >> 1) & 3);
            bfr[ni] = *(const bf16x8*)&Bv[row * 32 + c * 8];
        }
#pragma unroll
        for (int mi = 0; mi < 4; ++mi)
#pragma unroll
            for (int ni = 0; ni < 4; ++ni)
                acc[mi][ni] = mfma16(af[mi], bfr[ni], acc[mi][ni]);
        __syncthreads();
    }
#undef STAGE

    // epilogue: restage C-tile in LDS, then coalesced 256B-row stores
    bf16* ct = (bf16*)&sm;           // 128x128 bf16 = 32KB
    const int b  = m0 / Sq;
    const int s0 = m0 % Sq;
    const int h  = n0 >> 8;
    const int d0 = n0 & 255;
    const int bh = b * Hq + h;

    if (sel == 1) {
#pragma unroll
        for (int mi = 0; mi < 4; ++mi)
#pragma unroll
            for (int ni = 0; ni < 4; ++ni)
#pragma unroll
                for (int r = 0; r < 4; ++r) {
                    int row = wn + ni * 16 + l16;           // d_local
                    int col = wm + mi * 16 + quad * 4 + r;  // s_local
                    ct[row * 128 + (((col >> 3) ^ (row & 15)) * 8) + (col & 7)] =
                        __float2bfloat16(acc[mi][ni][r]);
                }
    } else {
#pragma unroll
        for (int mi = 0; mi < 4; ++mi)
#pragma unroll
            for (int ni = 0; ni < 4; ++ni)
#pragma unroll
                for (int r = 0; r < 4; ++r) {
                    int row = wm + mi * 16 + quad * 4 + r;  // s_local
                    int col = wn + ni * 16 + l16;           // n_local
                    ct[row * 128 + (((col >> 3) ^ (row & 15)) * 8) + (col & 7)] =
                        __float2bfloat16(acc[mi][ni][r]);
                }
    }
    __syncthreads();
    {
        const int rr = tid >> 4;   // 0..15
        const int c  = tid & 15;   // 0..15
#pragma unroll
        for (int p = 0; p < 8; ++p) {
            int r  = p * 16 + rr;
            int cp = c ^ (r & 15);
            bf16x8 v = *(const bf16x8*)&ct[r * 128 + cp * 8];
            if (sel == 1)
                *(bf16x8*)&Vt[(size_t)(bh * Dq + d0 + r) * Sq + s0 + c * 8] = v;
            else if (sel == 0)
                *(bf16x8*)&Kp[(size_t)(bh * Sq + s0 + r) * Dq + d0 + c * 8] = v;
            else
                *(bf16x8*)&Qp[(size_t)(bh * Sq + s0 + r) * Dq + d0 + c * 8] = v;
        }
    }
}

// ---------------------------------------------------------------------------
// Split-K flash attention — R9 kernel body EXACTLY (61.6us measured), with
// ONLY the work-distribution indexing changed: chunk size 8 -> 16 tiles.
// Slots/bh 80 -> 48, grid 960 -> 576 (= 8 XCDs x 72), singles qb<16 (half
// of all q-blocks write Z directly, bypassing Opart). Intra-bh dispatch
// order is INVERTED (w48 = 47 - W%48) so the 16-tile chunks launch first
// and 1-tile singles fill the scheduling tail (LPT ordering).
// Inner per-tile code, LDS layout, register profile untouched.
// ---------------------------------------------------------------------------
__global__ __launch_bounds__(256, 2) void attn_kernel(
        const bf16* __restrict__ Qp, const bf16* __restrict__ Kp,
        const bf16* __restrict__ Vt, bf16* __restrict__ Z,
        bf16* __restrict__ Opart, float* __restrict__ lpart) {
    __shared__ bf16 Ks[64 * 256];
    __shared__ bf16 Vs[256 * 64];
    __shared__ bf16 Pl[4 * 16 * 64];

    const float SCALE = 0.022097086912079608f;  // 1/sqrt(2048)

    const int id    = blockIdx.x;     // [0,576)
    const int lane8 = id & 7;         // XCD
    const int j     = id >> 3;        // [0,72)
    const int W     = lane8 * 72 + j;
    const int bh    = W / 48;
    const int w48   = 47 - (W % 48);  // long-chunks dispatch first
    int qb, chunk;
    if (w48 < 16) { qb = w48; chunk = 0; }
    else { int r = w48 - 16; qb = 16 + (r >> 1); chunk = r & 1; }
    const int t0    = chunk * 16;
    const int t1    = min(t0 + 16, qb + 1);
    const bool single = (qb < 16);

    const int tid  = threadIdx.x;
    const int lane = tid & 63;
    const int w    = tid >> 6;
    const int quad = lane >> 4;
    const int l16  = lane & 15;
    const int q0   = qb * 64 + w * 16;

    bf16x8 qf[8];
    {
        const bf16* Qbase = Qp + (size_t)(bh * Sq + q0 + l16) * Dq;
#pragma unroll
        for (int c = 0; c < 8; ++c)
            qf[c] = *(const bf16x8*)&Qbase[c * 32 + quad * 8];
    }

    const bf16* Kbh = Kp + (size_t)bh * Sq * Dq;
    const bf16* Vbh = Vt + (size_t)bh * Dq * Sq;

    f32x4 o[16] = {};
    float lsum[4] = {0.0f, 0.0f, 0.0f, 0.0f};

    for (int t = t0; t < t1; ++t) {
        const int k0 = t * 64;

        bf16x8 kreg[8], vreg[8];
#pragma unroll
        for (int p = 0; p < 8; ++p) {
            int c = p * 256 + tid;
            int row = c >> 5, cc = c & 31;
            kreg[p] = *(const bf16x8*)&Kbh[(size_t)(k0 + row) * Dq + cc * 8];
        }
#pragma unroll
        for (int p = 0; p < 8; ++p) {
            int c = p * 256 + tid;
            int row = c >> 3, cc = c & 7;
            vreg[p] = *(const bf16x8*)&Vbh[(size_t)row * Sq + k0 + cc * 8];
        }

        __syncthreads();
#pragma unroll
        for (int p = 0; p < 8; ++p) {
            int c = p * 256 + tid;
            int row = c >> 5, cc = c & 31;
            *(bf16x8*)&Ks[row * 256 + (cc ^ (row & 7)) * 8] = kreg[p];
        }
#pragma unroll
        for (int p = 0; p < 8; ++p) {
            int c = p * 256 + tid;
            int row = c >> 3, cc = c & 7;
            *(bf16x8*)&Vs[row * 64 + (cc ^ (row & 7)) * 8] = vreg[p];
        }
        __syncthreads();

        f32x4 sf[4] = {};
        __builtin_amdgcn_s_setprio(1);
#pragma unroll
        for (int c = 0; c < 8; ++c) {
            int cc = c * 4 + quad;
#pragma unroll
            for (int ni = 0; ni < 4; ++ni) {
                int key = ni * 16 + l16;
                bf16x8 kf = *(const bf16x8*)&Ks[key * 256 + (cc ^ (key & 7)) * 8];
                sf[ni] = mfma16(qf[c], kf, sf[ni]);
            }
        }
        __builtin_amdgcn_s_setprio(0);

        const bool diag = (t == qb);
#pragma unroll
        for (int ni = 0; ni < 4; ++ni) {
#pragma unroll
            for (int r = 0; r < 4; ++r) {
                float p = __expf(sf[ni][r] * SCALE);
                if (diag) {
                    int kg = k0 + ni * 16 + l16;
                    int qg = q0 + quad * 4 + r;
                    if (kg > qg) p = 0.0f;
                }
                lsum[r] += p;
                int row = quad * 4 + r;
                int col = ni * 16 + l16;
                int cc  = col >> 3;
                Pl[w * 1024 + row * 64 + (cc ^ (row & 7)) * 8 + (col & 7)] =
                    __float2bfloat16(p);
            }
        }

        __builtin_amdgcn_s_setprio(1);
#pragma unroll
        for (int c2 = 0; c2 < 2; ++c2) {
            int cc = c2 * 4 + quad;
            bf16x8 af = *(const bf16x8*)&Pl[w * 1024 + l16 * 64 + (cc ^ (l16 & 7)) * 8];
#pragma unroll
            for (int ni = 0; ni < 16; ++ni) {
                int d = ni * 16 + l16;
                bf16x8 vf = *(const bf16x8*)&Vs[d * 64 + (cc ^ (d & 7)) * 8];
                o[ni] = mfma16(af, vf, o[ni]);
            }
        }
        __builtin_amdgcn_s_setprio(0);
    }

#pragma unroll
    for (int off = 1; off < 16; off <<= 1)
#pragma unroll
        for (int r = 0; r < 4; ++r)
            lsum[r] += __shfl_xor(lsum[r], off);

    if (single) {
        const int b = bh / Hq, h = bh % Hq;
        float rinv[4];
#pragma unroll
        for (int r = 0; r < 4; ++r) rinv[r] = 1.0f / lsum[r];
#pragma unroll
        for (int ni = 0; ni < 16; ++ni) {
#pragma unroll
            for (int r = 0; r < 4; ++r) {
                int s = q0 + quad * 4 + r;
                int e = h * Dq + ni * 16 + l16;
                Z[(size_t)(b * Sq + s) * Eq + e] = __float2bfloat16(o[ni][r] * rinv[r]);
            }
        }
    } else {
        const int slot = bh * 48 + w48;
        bf16* Ob = Opart + (size_t)slot * (64 * 256);
#pragma unroll
        for (int ni = 0; ni < 16; ++ni) {
#pragma unroll
            for (int r = 0; r < 4; ++r) {
                int row = w * 16 + quad * 4 + r;
                int col = ni * 16 + l16;
                Ob[row * 256 + col] = __float2bfloat16(o[ni][r]);
            }
        }
        if (l16 == 0) {
#pragma unroll
            for (int r = 0; r < 4; ++r)
                lpart[(size_t)slot * 64 + w * 16 + quad * 4 + r] = lsum[r];
        }
    }
}

// ---------------------------------------------------------------------------
// Combine partials (chunk=16 indexing). Grid (16, 12): qb = blockIdx.x + 16,
// always nch = 2, slot0 = bh*48 + 16 + (qb-16)*2.
// ---------------------------------------------------------------------------
__global__ __launch_bounds__(256) void combine_kernel(
        const bf16* __restrict__ Opart, const float* __restrict__ lpart,
        bf16* __restrict__ Z) {
    const int qb = blockIdx.x + 16;
    const int bh = blockIdx.y;
    const int nch = 2;
    const int slot0 = bh * 48 + 16 + (qb - 16) * 2;

    const int tid = threadIdx.x;
    const int r   = tid >> 2;
    const int cs  = tid & 3;

    float l = 0.0f;
    for (int c = 0; c < nch; ++c)
        l += lpart[(size_t)(slot0 + c) * 64 + r];
    const float rinv = 1.0f / l;

    const int b = bh / Hq, h = bh % Hq;
    const int s = qb * 64 + r;
    bf16* zrow = Z + (size_t)(b * Sq + s) * Eq + h * Dq;

#pragma unroll
    for (int seg = 0; seg < 8; ++seg) {
        int col0 = cs * 64 + seg * 8;
        float acc[8] = {};
        for (int c = 0; c < nch; ++c) {
            bf16x8 v = *(const bf16x8*)&Opart[(size_t)(slot0 + c) * (64 * 256) + r * 256 + col0];
#pragma unroll
            for (int i = 0; i < 8; ++i) {
                short sv = v[i];
                acc[i] += bf2f(sv);
            }
        }
        bf16x8 outv;
#pragma unroll
        for (int i = 0; i < 8; ++i) outv[i] = f2bf(acc[i] * rinv);
        *(bf16x8*)&zrow[col0] = outv;
    }
}

// ---------------------------------------------------------------------------
// Output projection (R1 structure: double-buffered BK=32, one barrier/step).
// ---------------------------------------------------------------------------
__global__ __launch_bounds__(256) void outproj_kernel(
        const bf16* __restrict__ Z, const bf16* __restrict__ Wot,
        const float* __restrict__ bo, float* __restrict__ out) {
    const int x   = blockIdx.x;
    const int xcd = x & 7;
    const int kk0 = x >> 3;               // [0,48)
    const int mt  = xcd * 8 + (kk0 / 6);  // [0,64)
    const int nt  = kk0 % 6;              // [0,6)

    __shared__ bf16 As[2][128 * 32];
    __shared__ bf16 Bs[2][128 * 32];

    const int tid  = threadIdx.x;
    const int lane = tid & 63;
    const int w    = tid >> 6;
    const int quad = lane >> 4;
    const int l16  = lane & 15;
    const int wm   = (w & 1) * 64;
    const int wn   = (w >> 1) * 64;

    const int m0 = mt * 128;
    const int n0 = nt * 128;

    int srow[2], skc[2];
#pragma unroll
    for (int i = 0; i < 2; ++i) {
        int ci  = (w * 2 + i) * 64 + lane;
        srow[i] = ci >> 2;
        skc[i]  = (ci & 3) ^ ((srow[i] >> 1) & 3);
    }

#define STAGE2(buf, k0)                                                       \
    {                                                                         \
        _Pragma("unroll")                                                     \
        for (int i = 0; i < 2; ++i) {                                         \
            gl2lds16(&Z[(size_t)(m0 + srow[i]) * Eq + (k0) + skc[i] * 8],     \
                     &As[buf][(w * 2 + i) * 512]);                            \
            gl2lds16(&Wot[(size_t)(n0 + srow[i]) * Eq + (k0) + skc[i] * 8],   \
                     &Bs[buf][(w * 2 + i) * 512]);                            \
        }                                                                     \
    }

    STAGE2(0, 0);
    __syncthreads();

    f32x4 acc[4][4] = {};

    for (int s = 0; s < 24; ++s) {
        if (s + 1 < 24) STAGE2((s + 1) & 1, (s + 1) * 32);
        const bf16* A  = As[s & 1];
        const bf16* Bv = Bs[s & 1];
        bf16x8 af[4], bfr[4];
#pragma unroll
        for (int mi = 0; mi < 4; ++mi) {
            int row = wm + mi * 16 + l16;
            int c   = quad ^ ((row >> 1) & 3);
            af[mi]  = *(const bf16x8*)&A[row * 32 + c * 8];
        }
#pragma unroll
        for (int ni = 0; ni < 4; ++ni) {
            int row = wn + ni * 16 + l16;
            int c   = quad ^ ((row >> 1) & 3);
            bfr[ni] = *(const bf16x8*)&Bv[row * 32 + c * 8];
        }
#pragma unroll
        for (int mi = 0; mi < 4; ++mi)
#pragma unroll
            for (int ni = 0; ni < 4; ++ni)
                acc[mi][ni] = mfma16(af[mi], bfr[ni], acc[mi][ni]);
        __syncthreads();
    }
#undef STAGE2

#pragma unroll
    for (int ni = 0; ni < 4; ++ni) {
        int n = n0 + wn + ni * 16 + l16;
        float bias = bo[n];
#pragma unroll
        for (int mi = 0; mi < 4; ++mi) {
#pragma unroll
            for (int r = 0; r < 4; ++r) {
                int m = m0 + wm + mi * 16 + quad * 4 + r;
                out[(size_t)m * Eq + n] = acc[mi][ni][r] + bias;
            }
        }
    }
}

// ---------------------------------------------------------------------------
extern "C" void kernel_launch(void* const* d_in, const int* in_sizes, int n_in,
                              void* d_out, int out_size, void* d_ws, size_t ws_size,
                              hipStream_t stream) {
    const float* Xk = (const float*)d_in[0];
    const float* Xv = (const float*)d_in[1];
    const float* Xq = (const float*)d_in[2];
    const float* WK = (const float*)d_in[3];
    const float* WV = (const float*)d_in[4];
    const float* WQ = (const float*)d_in[5];
    const float* Wo = (const float*)d_in[6];
    const float* bo = (const float*)d_in[7];
    float* out = (float*)d_out;

    // workspace layout (bf16 elements)
    bf16* ws = (bf16*)d_ws;
    const size_t WSZ  = (size_t)Hq * Eq * Dq;   // 589824
    const size_t QKV  = (size_t)BHq * Sq * Dq;  // 6291456
    bf16* WtK = ws;                 // [t][h][d][e], t=0 K /1 V /2 Q
    bf16* WtO = WtK + 3 * WSZ;      // [out_e][in_e]
    bf16* Qp  = WtO + (size_t)Eq * Eq;
    bf16* Kp  = Qp + QKV;           // [b,h,s,d]
    bf16* Vt  = Kp + QKV;           // [b,h,d,s]
    bf16* Zb  = Vt + QKV;           // [b,s,e]
    bf16* Opart = Zb + QKV;         // 576 x 64 x 256 bf16 (18.9 MB)
    // Xb aliases Opart (proj reads Xb before attn writes Opart). Xb spans
    // 3*B*S*E = 37.75 MB > Opart, so lpart is placed after the Xb span.
    bf16* Xb = Opart;
    float* lpart = (float*)(Opart + (size_t)3 * Bq * Sq * Eq);

    prep_kernel<<<11520, 256, 0, stream>>>(Xk, Xv, Xq, Xb, WK, WV, WQ, Wo, WtK, WtO);
    proj_kernel<<<dim3(384, 3), 256, 0, stream>>>(Xb, WtK, Kp, Vt, Qp);
    attn_kernel<<<576, 256, 0, stream>>>(Qp, Kp, Vt, Zb, Opart, lpart);
    combine_kernel<<<dim3(16, BHq), 256, 0, stream>>>(Opart, lpart, Zb);
    outproj_kernel<<<384, 256, 0, stream>>>(Zb, WtO, bo, out);
}